// Round 2
// baseline (171.879 us; speedup 1.0000x reference)
//
#include <hip/hip_runtime.h>

#define B_ 4
#define C_ 256
#define N_ 4096
#define E_ 32

typedef _Float16 f16x8 __attribute__((ext_vector_type(8)));
typedef _Float16 f16x4 __attribute__((ext_vector_type(4)));
typedef float f32x4 __attribute__((ext_vector_type(4)));

#define LOG2E 1.44269504088896f

// xT column swizzle: breaks the 16-way LDS write conflict of the x
// transpose while keeping 16B alignment of the f16x8 fragment reads
// (swizzle unit = 8 f16 = 16 B; applied identically on write and read).
#define XSWZ(row, col) ((col) ^ ((((row) >> 2) & 7) << 3))

// ---------------------------------------------------------------------------
// Kernel 1: K/Q/V 1x1-conv projections via f16 MFMA. One matrix per block.
//   Kb[b][n][e] = f, Qb[b][n][e] = g * log2(e), Vb[b][e][n] = h.
// Block 768 (m==3, SINGLE block) converts Wo -> f16 and writes gamma.
// (R11 fixes kept: was 256 duplicate Wo-convert blocks -> cross-XCD
// same-line write storm; xT writes were 16-way bank conflicted -> XSWZ.)
// ---------------------------------------------------------------------------
__global__ __launch_bounds__(256) void proj_kernel(
    const float* __restrict__ x,
    const float* __restrict__ Wk, const float* __restrict__ bk,
    const float* __restrict__ Wq, const float* __restrict__ bq,
    const float* __restrict__ Wv, const float* __restrict__ bv,
    const float* __restrict__ Wo,
    _Float16* __restrict__ Qb, _Float16* __restrict__ Kb, _Float16* __restrict__ Vb,
    _Float16* __restrict__ Wof16, float* __restrict__ out)
{
    const int m = blockIdx.x >> 8;           // 0=K, 1=Q, 2=V, 3=Wo-convert
    if (m == 3) {
        for (int i4 = threadIdx.x; i4 < (C_ * E_) / 4; i4 += 256) {
            float4 wv = ((const float4*)Wo)[i4];
            f16x4 tp = {(_Float16)wv.x, (_Float16)wv.y, (_Float16)wv.z, (_Float16)wv.w};
            *(f16x4*)&Wof16[i4 * 4] = tp;
        }
        if (threadIdx.x == 0)
            out[(size_t)2 * B_ * C_ * N_] = 0.5f;   // gamma (non-learned)
        return;
    }
    const int rem = blockIdx.x & 255;
    const int b   = rem >> 6;
    const int n0  = (rem & 63) << 6;
    const int t    = threadIdx.x;
    const int lane = t & 63;
    const int wave = t >> 6;
    const int l15  = lane & 15;
    const int quad = lane >> 4;

    __shared__ _Float16 xT[64][264];   // x tile transposed: [n_local][c], XSWZ'd cols
    __shared__ _Float16 Wl[32][264];   // this matrix's weights: [e][c]

    const float* W    = (m == 0) ? Wk : (m == 1) ? Wq : Wv;
    const float* bias = (m == 0) ? bk : (m == 1) ? bq : bv;

    for (int i4 = t; i4 < (E_ * C_) / 4; i4 += 256) {
        float4 wv = ((const float4*)W)[i4];
        int e = (i4 * 4) >> 8, c = (i4 * 4) & 255;
        f16x4 tp = {(_Float16)wv.x, (_Float16)wv.y, (_Float16)wv.z, (_Float16)wv.w};
        *(f16x4*)&Wl[e][c] = tp;
    }
    for (int i4 = t; i4 < (64 * 256) / 4; i4 += 256) {
        int j4 = (i4 & 15) * 4;
        int c  = i4 >> 4;
        float4 xv = *(const float4*)(x + (size_t)(b * C_ + c) * N_ + n0 + j4);
        xT[j4 + 0][XSWZ(j4 + 0, c)] = (_Float16)xv.x;
        xT[j4 + 1][XSWZ(j4 + 1, c)] = (_Float16)xv.y;
        xT[j4 + 2][XSWZ(j4 + 2, c)] = (_Float16)xv.z;
        xT[j4 + 3][XSWZ(j4 + 3, c)] = (_Float16)xv.w;
    }
    __syncthreads();

    const int row = wave * 16 + l15;
    f16x8 Bf[8];
    for (int kk = 0; kk < 8; ++kk)
        Bf[kk] = *(const f16x8*)&xT[row][XSWZ(row, kk * 32 + quad * 8)];

    const float sc = (m == 1) ? LOG2E : 1.0f;
    for (int et = 0; et < 2; ++et) {
        f32x4 acc = {0.f, 0.f, 0.f, 0.f};
        for (int kk = 0; kk < 8; ++kk) {
            f16x8 Af = *(const f16x8*)&Wl[et * 16 + l15][kk * 32 + quad * 8];
            acc = __builtin_amdgcn_mfma_f32_16x16x32_f16(Af, Bf[kk], acc, 0, 0, 0);
        }
        const int n  = n0 + wave * 16 + l15;
        const int e0 = et * 16 + quad * 4;
        if (m == 2) {
            for (int r = 0; r < 4; ++r)
                Vb[(size_t)(b * E_ + e0 + r) * N_ + n] =
                    (_Float16)(acc[r] + bias[e0 + r]);
        } else {
            f16x4 st;
            for (int r = 0; r < 4; ++r)
                st[r] = (_Float16)((acc[r] + bias[e0 + r]) * sc);
            _Float16* dst = (m == 0) ? Kb : Qb;
            *(f16x4*)&dst[(size_t)(b * N_ + n) * E_ + e0] = st;
        }
    }
}

// ---------------------------------------------------------------------------
// Kernel 2: flash attention + fused output projection.
// R12 vs R10: the QK^T D-layout (lane holds S[i=4*quad+r][j=l15]) is
// EXACTLY the B-frag layout of mfma_f32_16x16x16_f16 (k = quad*4+e).
// So PV uses 4x 16x16x16 MFMA (2 key-slabs x 2 e-halves) and P feeds it
// straight from registers: no LDS round-trip, no cross-lane ops, no
// inline asm. Same FLOPs as 2x 16x16x32. Also kept from R11:
//  - register-rotating K/V prefetch (next tile's loads covered by the
//    whole softmax+PV phase),
//  - defer-rescale (THR=8, log2 domain, wave-uniform __any; P <= 2^8
//    is exact in f16 and the LSE combine is reference-point invariant).
// ---------------------------------------------------------------------------
__global__ __launch_bounds__(512, 6) void attn_kernel(
    const _Float16* __restrict__ Qb, const _Float16* __restrict__ Kb,
    const _Float16* __restrict__ Vb, const _Float16* __restrict__ Wof16,
    const float* __restrict__ bo, const float* __restrict__ x,
    float* __restrict__ out)
{
    const int wave = threadIdx.x >> 6;     // i-split 0..7
    const int lane = threadIdx.x & 63;
    const int l15  = lane & 15, quad = lane >> 4;
    const int jg   = blockIdx.x;           // 0..1023
    const int b    = jg >> 8;
    const int j0   = (jg & 255) << 4;

    // pbuf only used after the loop (osum overlay); the K-loop is LDS-free.
    __shared__ __align__(16) char pbuf[8][2176];
    __shared__ float    mls[8][2][16];     // per-wave (m, l) per j
    __shared__ _Float16 Om[16][40];        // merged O rows (f16), b128 rows

    // Q B-frag: B[k=e][n=j], lane j=l15, k=quad*8.. from Qb[j][e]
    f16x8 Qf = *(const f16x8*)(Qb + (size_t)(b * N_ + j0 + l15) * E_ + quad * 8);

    f32x4 O0 = {0, 0, 0, 0}, O1 = {0, 0, 0, 0};   // O^T[e][j]
    float mrow = -1e30f, lsum = 0.f;               // per-lane (per-j) state

    const _Float16* Kp = Kb + (size_t)b * N_ * E_ + (size_t)(wave << 9) * E_;
    const _Float16* Vp = Vb + (size_t)b * E_ * N_ + (wave << 9);

    // prologue loads (it = 0)
    f16x8 K0  = *(const f16x8*)(Kp + (size_t)l15 * E_ + quad * 8);
    f16x8 K1  = *(const f16x8*)(Kp + (size_t)(16 + l15) * E_ + quad * 8);
    f16x4 Va0 = *(const f16x4*)(Vp + (size_t)l15 * N_ + quad * 4);
    f16x4 Va1 = *(const f16x4*)(Vp + (size_t)l15 * N_ + 16 + quad * 4);
    f16x4 Vc0 = *(const f16x4*)(Vp + (size_t)(16 + l15) * N_ + quad * 4);
    f16x4 Vc1 = *(const f16x4*)(Vp + (size_t)(16 + l15) * N_ + 16 + quad * 4);

    for (int it = 0; it < 16; ++it) {
        f32x4 z = {0, 0, 0, 0};
        f32x4 S0 = __builtin_amdgcn_mfma_f32_16x16x32_f16(K0, Qf, z, 0, 0, 0);
        f32x4 S1 = __builtin_amdgcn_mfma_f32_16x16x32_f16(K1, Qf, z, 0, 0, 0);
        // prefetch next iteration's K (same regs; wraps to it=0 on last iter)
        const int i0n = ((it + 1) & 15) << 5;
        K0 = *(const f16x8*)(Kp + (size_t)(i0n + l15) * E_ + quad * 8);
        K1 = *(const f16x8*)(Kp + (size_t)(i0n + 16 + l15) * E_ + quad * 8);

        // column max over the 8 in-lane scores + quad reduce
        float mx = fmaxf(fmaxf(fmaxf(S0[0], S0[1]), fmaxf(S0[2], S0[3])),
                         fmaxf(fmaxf(S1[0], S1[1]), fmaxf(S1[2], S1[3])));
        mx = fmaxf(mx, __shfl_xor(mx, 16));
        mx = fmaxf(mx, __shfl_xor(mx, 32));
        // defer-rescale: only pay alpha/rescale when max grew by >8
        if (__any(mx > mrow + 8.f)) {
            float mnew  = fmaxf(mrow, mx);
            float alpha = exp2f(mrow - mnew);          // log2 domain
            mrow = mnew;
            lsum *= alpha;
            O0 *= alpha;
            O1 *= alpha;
        }
        float p00 = exp2f(S0[0] - mrow), p01 = exp2f(S0[1] - mrow);
        float p02 = exp2f(S0[2] - mrow), p03 = exp2f(S0[3] - mrow);
        float p10 = exp2f(S1[0] - mrow), p11 = exp2f(S1[1] - mrow);
        float p12 = exp2f(S1[2] - mrow), p13 = exp2f(S1[3] - mrow);
        lsum += ((p00 + p01) + (p02 + p03)) + ((p10 + p11) + (p12 + p13));

        // P stays in-lane: D-layout == 16x16x16 B-frag layout (k = 4q+e).
        f16x4 P0 = {(_Float16)p00, (_Float16)p01, (_Float16)p02, (_Float16)p03};
        f16x4 P1 = {(_Float16)p10, (_Float16)p11, (_Float16)p12, (_Float16)p13};

        // PV: O^T += V x P, two 16-key slabs, two e-halves (interleaved
        // so the O0/O1 dependency chains overlap)
        O0 = __builtin_amdgcn_mfma_f32_16x16x16f16(Va0, P0, O0, 0, 0, 0);
        O1 = __builtin_amdgcn_mfma_f32_16x16x16f16(Vc0, P0, O1, 0, 0, 0);
        O0 = __builtin_amdgcn_mfma_f32_16x16x16f16(Va1, P1, O0, 0, 0, 0);
        O1 = __builtin_amdgcn_mfma_f32_16x16x16f16(Vc1, P1, O1, 0, 0, 0);

        // prefetch next iteration's V (same regs)
        Va0 = *(const f16x4*)(Vp + (size_t)l15 * N_ + i0n + quad * 4);
        Va1 = *(const f16x4*)(Vp + (size_t)l15 * N_ + i0n + 16 + quad * 4);
        Vc0 = *(const f16x4*)(Vp + (size_t)(16 + l15) * N_ + i0n + quad * 4);
        Vc1 = *(const f16x4*)(Vp + (size_t)(16 + l15) * N_ + i0n + 16 + quad * 4);
    }

    // finish per-split l (sum over quads), publish (m, l)
    lsum += __shfl_xor(lsum, 16);
    lsum += __shfl_xor(lsum, 32);
    if (quad == 0) { mls[wave][0][l15] = mrow; mls[wave][1][l15] = lsum; }
    __syncthreads();

    // log-sum-exp combine weights across 8 splits (redundant per quad)
    float M = -1e30f, ms[8], ls[8];
    for (int s = 0; s < 8; ++s) {
        ms[s] = mls[s][0][l15]; ls[s] = mls[s][1][l15];
        M = fmaxf(M, ms[s]);
    }
    float L = 0.f;
    for (int s = 0; s < 8; ++s) L += ls[s] * exp2f(ms[s] - M);
    const float w = exp2f(mrow - M) / L;

    // osum in pbuf (phase 2)
    float (*osum)[34] = (float (*)[34])(pbuf[wave]);
    *(f32x4*)&osum[l15][quad * 4]      = O0 * w;
    *(f32x4*)&osum[l15][16 + quad * 4] = O1 * w;
    __syncthreads();

    // cross-split sum -> merged O row (f16) in LDS; one thread per (j, e)
    {
        const int j = threadIdx.x >> 5;    // 0..15
        const int e = threadIdx.x & 31;    // 0..31
        float a = 0.f;
        for (int s = 0; s < 8; ++s)
            a += ((const float (*)[34])(pbuf[s]))[j][e];
        Om[j][e] = (_Float16)a;
    }
    __syncthreads();

    // ---- fused output projection: each wave covers 32 channels ----
    f16x8 Bf2 = *(const f16x8*)&Om[l15][quad * 8];
    float* out_y = out + (size_t)b * C_ * N_;
    float* out_o = out + (size_t)B_ * C_ * N_ + (size_t)b * C_ * N_;
    const float* xb = x + (size_t)b * C_ * N_;
    for (int ct = 0; ct < 2; ++ct) {
        const int c0 = wave * 32 + ct * 16;
        f16x8 Af = *(const f16x8*)(Wof16 + (size_t)(c0 + l15) * E_ + quad * 8);
        f32x4 z = {0, 0, 0, 0};
        f32x4 acc = __builtin_amdgcn_mfma_f32_16x16x32_f16(Af, Bf2, z, 0, 0, 0);
        for (int r = 0; r < 4; ++r) {
            const int c = c0 + quad * 4 + r;
            size_t idx = (size_t)c * N_ + j0 + l15;
            float ov = acc[r] + bo[c];
            out_o[idx] = ov;
            out_y[idx] = 0.5f * ov + xb[idx];
        }
    }
}

// ---------------------------------------------------------------------------
extern "C" void kernel_launch(void* const* d_in, const int* in_sizes, int n_in,
                              void* d_out, int out_size, void* d_ws, size_t ws_size,
                              hipStream_t stream)
{
    const float* x  = (const float*)d_in[0];
    const float* Wk = (const float*)d_in[1];
    const float* bk = (const float*)d_in[2];
    const float* Wq = (const float*)d_in[3];
    const float* bq = (const float*)d_in[4];
    const float* Wv = (const float*)d_in[5];
    const float* bv = (const float*)d_in[6];
    const float* Wo = (const float*)d_in[7];
    const float* bo = (const float*)d_in[8];
    float* out = (float*)d_out;

    char* ws = (char*)d_ws;
    _Float16* Qb    = (_Float16*)(ws);                   // 1 MB  [B][N][E]
    _Float16* Kb    = (_Float16*)(ws + (1u << 20));      // 1 MB  [B][N][E]
    _Float16* Vb    = (_Float16*)(ws + (2u << 20));      // 1 MB  [B][E][N]
    _Float16* Wof16 = (_Float16*)(ws + (3u << 20));      // 16 KB [C][E]

    // 768 projection blocks + 1 (not 256!) Wo-convert block
    proj_kernel<<<dim3(3 * B_ * (N_ / 64) + 1), dim3(256), 0, stream>>>(
        x, Wk, bk, Wq, bq, Wv, bv, Wo, Qb, Kb, Vb, Wof16, out);
    attn_kernel<<<dim3(B_ * (N_ / 16)), dim3(512), 0, stream>>>(
        Qb, Kb, Vb, Wof16, bo, x, out);
}

// Round 4
// 145.749 us; speedup vs baseline: 1.1793x; 1.1793x over previous
//
#include <hip/hip_runtime.h>

#define B_ 4
#define C_ 256
#define N_ 4096
#define E_ 32

typedef _Float16 f16x8 __attribute__((ext_vector_type(8)));
typedef _Float16 f16x4 __attribute__((ext_vector_type(4)));
typedef float f32x4 __attribute__((ext_vector_type(4)));

#define LOG2E 1.44269504088896f

// xT column swizzle: breaks the 16-way LDS write conflict of the x
// transpose while keeping 16B alignment of the f16x8 fragment reads
// (swizzle unit = 8 f16 = 16 B; applied identically on write and read).
#define XSWZ(row, col) ((col) ^ ((((row) >> 2) & 7) << 3))

// ---------------------------------------------------------------------------
// Kernel 1: K/Q/V 1x1-conv projections via f16 MFMA. One matrix per block.
//   Kb[b][n][e] = f, Qb[b][n][e] = g * log2(e), Vb[b][e][n] = h.
// Block 768 (m==3, SINGLE block) converts Wo -> f16 and writes gamma.
// ---------------------------------------------------------------------------
__global__ __launch_bounds__(256) void proj_kernel(
    const float* __restrict__ x,
    const float* __restrict__ Wk, const float* __restrict__ bk,
    const float* __restrict__ Wq, const float* __restrict__ bq,
    const float* __restrict__ Wv, const float* __restrict__ bv,
    const float* __restrict__ Wo,
    _Float16* __restrict__ Qb, _Float16* __restrict__ Kb, _Float16* __restrict__ Vb,
    _Float16* __restrict__ Wof16, float* __restrict__ out)
{
    const int m = blockIdx.x >> 8;           // 0=K, 1=Q, 2=V, 3=Wo-convert
    if (m == 3) {
        for (int i4 = threadIdx.x; i4 < (C_ * E_) / 4; i4 += 256) {
            float4 wv = ((const float4*)Wo)[i4];
            f16x4 tp = {(_Float16)wv.x, (_Float16)wv.y, (_Float16)wv.z, (_Float16)wv.w};
            *(f16x4*)&Wof16[i4 * 4] = tp;
        }
        if (threadIdx.x == 0)
            out[(size_t)2 * B_ * C_ * N_] = 0.5f;   // gamma (non-learned)
        return;
    }
    const int rem = blockIdx.x & 255;
    const int b   = rem >> 6;
    const int n0  = (rem & 63) << 6;
    const int t    = threadIdx.x;
    const int lane = t & 63;
    const int wave = t >> 6;
    const int l15  = lane & 15;
    const int quad = lane >> 4;

    __shared__ _Float16 xT[64][264];   // x tile transposed: [n_local][c], XSWZ'd cols
    __shared__ _Float16 Wl[32][264];   // this matrix's weights: [e][c]

    const float* W    = (m == 0) ? Wk : (m == 1) ? Wq : Wv;
    const float* bias = (m == 0) ? bk : (m == 1) ? bq : bv;

    for (int i4 = t; i4 < (E_ * C_) / 4; i4 += 256) {
        float4 wv = ((const float4*)W)[i4];
        int e = (i4 * 4) >> 8, c = (i4 * 4) & 255;
        f16x4 tp = {(_Float16)wv.x, (_Float16)wv.y, (_Float16)wv.z, (_Float16)wv.w};
        *(f16x4*)&Wl[e][c] = tp;
    }
    for (int i4 = t; i4 < (64 * 256) / 4; i4 += 256) {
        int j4 = (i4 & 15) * 4;
        int c  = i4 >> 4;
        float4 xv = *(const float4*)(x + (size_t)(b * C_ + c) * N_ + n0 + j4);
        xT[j4 + 0][XSWZ(j4 + 0, c)] = (_Float16)xv.x;
        xT[j4 + 1][XSWZ(j4 + 1, c)] = (_Float16)xv.y;
        xT[j4 + 2][XSWZ(j4 + 2, c)] = (_Float16)xv.z;
        xT[j4 + 3][XSWZ(j4 + 3, c)] = (_Float16)xv.w;
    }
    __syncthreads();

    const int row = wave * 16 + l15;
    f16x8 Bf[8];
    for (int kk = 0; kk < 8; ++kk)
        Bf[kk] = *(const f16x8*)&xT[row][XSWZ(row, kk * 32 + quad * 8)];

    const float sc = (m == 1) ? LOG2E : 1.0f;
    for (int et = 0; et < 2; ++et) {
        f32x4 acc = {0.f, 0.f, 0.f, 0.f};
        for (int kk = 0; kk < 8; ++kk) {
            f16x8 Af = *(const f16x8*)&Wl[et * 16 + l15][kk * 32 + quad * 8];
            acc = __builtin_amdgcn_mfma_f32_16x16x32_f16(Af, Bf[kk], acc, 0, 0, 0);
        }
        const int n  = n0 + wave * 16 + l15;
        const int e0 = et * 16 + quad * 4;
        if (m == 2) {
            for (int r = 0; r < 4; ++r)
                Vb[(size_t)(b * E_ + e0 + r) * N_ + n] =
                    (_Float16)(acc[r] + bias[e0 + r]);
        } else {
            f16x4 st;
            for (int r = 0; r < 4; ++r)
                st[r] = (_Float16)((acc[r] + bias[e0 + r]) * sc);
            _Float16* dst = (m == 0) ? Kb : Qb;
            *(f16x4*)&dst[(size_t)(b * N_ + n) * E_ + e0] = st;
        }
    }
}

// ---------------------------------------------------------------------------
// Kernel 2: flash attention + fused output projection.
// R13 = R10's PROVEN loop body (LDS P bounce + 2x independent 16x16x32 PV;
// R12 showed the legacy 16x16x16 PV chain added an MFMA-latency hop and
// scaled duration 1.5x) + the two R12-validated additions:
//  - register-rotating K/V prefetch: loads for iter it+1 issue right after
//    their consumers in iter it, so the QK MFMA never waits on L2 (~200-300
//    cyc removed from the per-iter dependent chain);
//  - defer-rescale (THR=8, log2 domain, wave-uniform __any).
// Every pipe shows <31% busy -> latency-chain bound; the only lever is
// shortening the chain, not the work.
// ---------------------------------------------------------------------------
__global__ __launch_bounds__(512, 6) void attn_kernel(
    const _Float16* __restrict__ Qb, const _Float16* __restrict__ Kb,
    const _Float16* __restrict__ Vb, const _Float16* __restrict__ Wof16,
    const float* __restrict__ bo, const float* __restrict__ x,
    float* __restrict__ out)
{
    const int wave = threadIdx.x >> 6;     // i-split 0..7
    const int lane = threadIdx.x & 63;
    const int l15  = lane & 15, quad = lane >> 4;
    const int jg   = blockIdx.x;           // 0..1023
    const int b    = jg >> 8;
    const int j0   = (jg & 255) << 4;

    // per-wave 2176 B region: phase 1 = pb [16][40] f16 (1280 B);
    // phase 2 = osum [16][34] f32 (2176 B) overlay (barrier-separated).
    __shared__ __align__(16) char pbuf[8][2176];
    __shared__ float    mls[8][2][16];     // per-wave (m, l) per j
    __shared__ _Float16 Om[16][40];        // merged O rows (f16), b128 rows

    _Float16 (*pb)[40] = (_Float16 (*)[40])(pbuf[wave]);

    // Q B-frag: B[k=e][n=j], lane j=l15, k=quad*8.. from Qb[j][e]
    f16x8 Qf = *(const f16x8*)(Qb + (size_t)(b * N_ + j0 + l15) * E_ + quad * 8);

    f32x4 O0 = {0, 0, 0, 0}, O1 = {0, 0, 0, 0};   // O^T[e][j]
    float mrow = -1e30f, lsum = 0.f;               // per-lane (per-j) state

    const _Float16* Kp = Kb + (size_t)b * N_ * E_ + (size_t)(wave << 9) * E_;
    const _Float16* Vp = Vb + (size_t)b * E_ * N_ + (wave << 9);

    // prologue loads (it = 0)
    f16x8 K0 = *(const f16x8*)(Kp + (size_t)l15 * E_ + quad * 8);
    f16x8 K1 = *(const f16x8*)(Kp + (size_t)(16 + l15) * E_ + quad * 8);
    f16x8 Va = *(const f16x8*)(Vp + (size_t)l15 * N_ + quad * 8);
    f16x8 Vc = *(const f16x8*)(Vp + (size_t)(16 + l15) * N_ + quad * 8);

    for (int it = 0; it < 16; ++it) {
        f32x4 z = {0, 0, 0, 0};
        f32x4 S0 = __builtin_amdgcn_mfma_f32_16x16x32_f16(K0, Qf, z, 0, 0, 0);
        f32x4 S1 = __builtin_amdgcn_mfma_f32_16x16x32_f16(K1, Qf, z, 0, 0, 0);
        // prefetch next iteration's K (same SSA names; wraps to it=0 on the
        // last iter: L2-hot, harmless)
        const int i0n = ((it + 1) & 15) << 5;
        K0 = *(const f16x8*)(Kp + (size_t)(i0n + l15) * E_ + quad * 8);
        K1 = *(const f16x8*)(Kp + (size_t)(i0n + 16 + l15) * E_ + quad * 8);

        // column max over the 8 in-lane scores + quad reduce
        float mx = fmaxf(fmaxf(fmaxf(S0[0], S0[1]), fmaxf(S0[2], S0[3])),
                         fmaxf(fmaxf(S1[0], S1[1]), fmaxf(S1[2], S1[3])));
        mx = fmaxf(mx, __shfl_xor(mx, 16));
        mx = fmaxf(mx, __shfl_xor(mx, 32));
        // defer-rescale: only pay alpha/rescale when max grew by >8
        if (__any(mx > mrow + 8.f)) {
            float mnew  = fmaxf(mrow, mx);
            float alpha = exp2f(mrow - mnew);          // log2 domain
            mrow = mnew;
            lsum *= alpha;
            O0 *= alpha;
            O1 *= alpha;
        }
        float p00 = exp2f(S0[0] - mrow), p01 = exp2f(S0[1] - mrow);
        float p02 = exp2f(S0[2] - mrow), p03 = exp2f(S0[3] - mrow);
        float p10 = exp2f(S1[0] - mrow), p11 = exp2f(S1[1] - mrow);
        float p12 = exp2f(S1[2] - mrow), p13 = exp2f(S1[3] - mrow);
        lsum += ((p00 + p01) + (p02 + p03)) + ((p10 + p11) + (p12 + p13));

        // P^T (D-layout) -> B-frag layout via per-wave LDS (2 x b64 write,
        // 1 x b128 read; compiler inserts the precise lgkmcnt). Measured:
        // this bounce costs ~0.6 us total across the dispatch — NOT the
        // bottleneck (R12 lesson).
        f16x4 w0 = {(_Float16)p00, (_Float16)p01, (_Float16)p02, (_Float16)p03};
        f16x4 w1 = {(_Float16)p10, (_Float16)p11, (_Float16)p12, (_Float16)p13};
        *(f16x4*)&pb[l15][quad * 4]      = w0;
        *(f16x4*)&pb[l15][16 + quad * 4] = w1;
        f16x8 P = *(const f16x8*)&pb[l15][quad * 8];

        // PV: O^T += V x P (two INDEPENDENT 16x16x32 MFMAs — one latency hop)
        O0 = __builtin_amdgcn_mfma_f32_16x16x32_f16(Va, P, O0, 0, 0, 0);
        O1 = __builtin_amdgcn_mfma_f32_16x16x32_f16(Vc, P, O1, 0, 0, 0);
        // prefetch next iteration's V (same SSA names)
        Va = *(const f16x8*)(Vp + (size_t)l15 * N_ + i0n + quad * 8);
        Vc = *(const f16x8*)(Vp + (size_t)(16 + l15) * N_ + i0n + quad * 8);
    }

    // finish per-split l (sum over quads), publish (m, l)
    lsum += __shfl_xor(lsum, 16);
    lsum += __shfl_xor(lsum, 32);
    if (quad == 0) { mls[wave][0][l15] = mrow; mls[wave][1][l15] = lsum; }
    __syncthreads();   // <- all pb reads complete before this barrier

    // log-sum-exp combine weights across 8 splits (redundant per quad)
    float M = -1e30f, ms[8], ls[8];
    for (int s = 0; s < 8; ++s) {
        ms[s] = mls[s][0][l15]; ls[s] = mls[s][1][l15];
        M = fmaxf(M, ms[s]);
    }
    float L = 0.f;
    for (int s = 0; s < 8; ++s) L += ls[s] * exp2f(ms[s] - M);
    const float w = exp2f(mrow - M) / L;

    // osum overlays pb (phase 2)
    float (*osum)[34] = (float (*)[34])(pbuf[wave]);
    *(f32x4*)&osum[l15][quad * 4]      = O0 * w;
    *(f32x4*)&osum[l15][16 + quad * 4] = O1 * w;
    __syncthreads();

    // cross-split sum -> merged O row (f16) in LDS; one thread per (j, e)
    {
        const int j = threadIdx.x >> 5;    // 0..15
        const int e = threadIdx.x & 31;    // 0..31
        float a = 0.f;
        for (int s = 0; s < 8; ++s)
            a += ((const float (*)[34])(pbuf[s]))[j][e];
        Om[j][e] = (_Float16)a;
    }
    __syncthreads();

    // ---- fused output projection: each wave covers 32 channels ----
    f16x8 Bf2 = *(const f16x8*)&Om[l15][quad * 8];
    float* out_y = out + (size_t)b * C_ * N_;
    float* out_o = out + (size_t)B_ * C_ * N_ + (size_t)b * C_ * N_;
    const float* xb = x + (size_t)b * C_ * N_;
    for (int ct = 0; ct < 2; ++ct) {
        const int c0 = wave * 32 + ct * 16;
        f16x8 Af = *(const f16x8*)(Wof16 + (size_t)(c0 + l15) * E_ + quad * 8);
        f32x4 z = {0, 0, 0, 0};
        f32x4 acc = __builtin_amdgcn_mfma_f32_16x16x32_f16(Af, Bf2, z, 0, 0, 0);
        for (int r = 0; r < 4; ++r) {
            const int c = c0 + quad * 4 + r;
            size_t idx = (size_t)c * N_ + j0 + l15;
            float ov = acc[r] + bo[c];
            out_o[idx] = ov;
            out_y[idx] = 0.5f * ov + xb[idx];
        }
    }
}

// ---------------------------------------------------------------------------
extern "C" void kernel_launch(void* const* d_in, const int* in_sizes, int n_in,
                              void* d_out, int out_size, void* d_ws, size_t ws_size,
                              hipStream_t stream)
{
    const float* x  = (const float*)d_in[0];
    const float* Wk = (const float*)d_in[1];
    const float* bk = (const float*)d_in[2];
    const float* Wq = (const float*)d_in[3];
    const float* bq = (const float*)d_in[4];
    const float* Wv = (const float*)d_in[5];
    const float* bv = (const float*)d_in[6];
    const float* Wo = (const float*)d_in[7];
    const float* bo = (const float*)d_in[8];
    float* out = (float*)d_out;

    char* ws = (char*)d_ws;
    _Float16* Qb    = (_Float16*)(ws);                   // 1 MB  [B][N][E]
    _Float16* Kb    = (_Float16*)(ws + (1u << 20));      // 1 MB  [B][N][E]
    _Float16* Vb    = (_Float16*)(ws + (2u << 20));      // 1 MB  [B][E][N]
    _Float16* Wof16 = (_Float16*)(ws + (3u << 20));      // 16 KB [C][E]

    // 768 projection blocks + 1 Wo-convert block
    proj_kernel<<<dim3(3 * B_ * (N_ / 64) + 1), dim3(256), 0, stream>>>(
        x, Wk, bk, Wq, bq, Wv, bv, Wo, Qb, Kb, Vb, Wof16, out);
    attn_kernel<<<dim3(B_ * (N_ / 16)), dim3(512), 0, stream>>>(
        Qb, Kb, Vb, Wof16, bo, x, out);
}

// Round 5
// 136.935 us; speedup vs baseline: 1.2552x; 1.0644x over previous
//
#include <hip/hip_runtime.h>

#define B_ 4
#define C_ 256
#define N_ 4096
#define E_ 32

typedef _Float16 f16x8 __attribute__((ext_vector_type(8)));
typedef _Float16 f16x4 __attribute__((ext_vector_type(4)));
typedef float f32x4 __attribute__((ext_vector_type(4)));

#define LOG2E 1.44269504088896f

// LDS column swizzle: breaks bank conflicts of row-strided b128 reads while
// keeping 16B alignment (swizzle unit = 8 f16 = 16 B; same on write & read).
#define XSWZ(row, col) ((col) ^ ((((row) >> 2) & 7) << 3))

// ---------------------------------------------------------------------------
// Kernel 1 (R14): ONE block per x-tile computes ALL THREE projections.
//   x staged once (was 3x across K/Q/V block types -> 50 MB HBM, now 17 MB).
//   Weights staged per-m sequentially into one Wl buffer (3 sync phases).
//   V written in TILED layout Vt[b][n/32][e][n%32] via an LDS transpose, so
//   attn's V loads become 1KB-contiguous (was a 16-segment 8KB-stride gather
//   = the L2 request storm) and proj's V stores become f16x8 (were scalar).
// Block 256 converts Wo -> f16 and writes gamma.
// ---------------------------------------------------------------------------
__global__ __launch_bounds__(256) void proj_kernel(
    const float* __restrict__ x,
    const float* __restrict__ Wk, const float* __restrict__ bk,
    const float* __restrict__ Wq, const float* __restrict__ bq,
    const float* __restrict__ Wv, const float* __restrict__ bv,
    const float* __restrict__ Wo,
    _Float16* __restrict__ Qb, _Float16* __restrict__ Kb, _Float16* __restrict__ Vt,
    _Float16* __restrict__ Wof16, float* __restrict__ out)
{
    if (blockIdx.x == 256) {                 // Wo-convert + gamma (single block)
        for (int i4 = threadIdx.x; i4 < (C_ * E_) / 4; i4 += 256) {
            float4 wv = ((const float4*)Wo)[i4];
            f16x4 tp = {(_Float16)wv.x, (_Float16)wv.y, (_Float16)wv.z, (_Float16)wv.w};
            *(f16x4*)&Wof16[i4 * 4] = tp;
        }
        if (threadIdx.x == 0)
            out[(size_t)2 * B_ * C_ * N_] = 0.5f;   // gamma (non-learned)
        return;
    }
    const int b  = blockIdx.x >> 6;
    const int n0 = (blockIdx.x & 63) << 6;
    const int t    = threadIdx.x;
    const int lane = t & 63;
    const int wave = t >> 6;
    const int l15  = lane & 15;
    const int quad = lane >> 4;

    __shared__ _Float16 xT[64][264];   // x tile transposed [n_local][c], XSWZ'd
    __shared__ _Float16 Wl[32][264];   // current matrix's weights [e][c], XSWZ'd
    __shared__ _Float16 vT[32][72];    // V transpose staging [e][n_local]

    // stage x tile once (float4 rows, contiguous 256B per c-row)
    for (int i4 = t; i4 < (64 * 256) / 4; i4 += 256) {
        int j4 = (i4 & 15) * 4;
        int c  = i4 >> 4;
        float4 xv = *(const float4*)(x + (size_t)(b * C_ + c) * N_ + n0 + j4);
        xT[j4 + 0][XSWZ(j4 + 0, c)] = (_Float16)xv.x;
        xT[j4 + 1][XSWZ(j4 + 1, c)] = (_Float16)xv.y;
        xT[j4 + 2][XSWZ(j4 + 2, c)] = (_Float16)xv.z;
        xT[j4 + 3][XSWZ(j4 + 3, c)] = (_Float16)xv.w;
    }

    const float* Ws[3] = {Wk, Wq, Wv};
    const float* bs[3] = {bk, bq, bv};

    const int row = wave * 16 + l15;
    f16x8 Bf[8];                      // x fragments, read once after 1st sync

    for (int m = 0; m < 3; ++m) {
        // stage this matrix's weights (L2-hot after first block)
        for (int i4 = t; i4 < (E_ * C_) / 4; i4 += 256) {
            float4 wv = ((const float4*)Ws[m])[i4];
            int e = (i4 * 4) >> 8, c = (i4 * 4) & 255;
            f16x4 tp = {(_Float16)wv.x, (_Float16)wv.y, (_Float16)wv.z, (_Float16)wv.w};
            *(f16x4*)&Wl[e][XSWZ(e, c)] = tp;
        }
        __syncthreads();
        if (m == 0) {
            #pragma unroll
            for (int kk = 0; kk < 8; ++kk)
                Bf[kk] = *(const f16x8*)&xT[row][XSWZ(row, kk * 32 + quad * 8)];
        }
        const float sc = (m == 1) ? LOG2E : 1.0f;
        const float* bias = bs[m];
        #pragma unroll
        for (int et = 0; et < 2; ++et) {
            f32x4 acc = {0.f, 0.f, 0.f, 0.f};
            #pragma unroll
            for (int kk = 0; kk < 8; ++kk) {
                const int e = et * 16 + l15;
                f16x8 Af = *(const f16x8*)&Wl[e][XSWZ(e, kk * 32 + quad * 8)];
                acc = __builtin_amdgcn_mfma_f32_16x16x32_f16(Af, Bf[kk], acc, 0, 0, 0);
            }
            const int n  = n0 + wave * 16 + l15;
            const int e0 = et * 16 + quad * 4;
            if (m == 2) {
                #pragma unroll
                for (int r = 0; r < 4; ++r)
                    vT[e0 + r][wave * 16 + l15] = (_Float16)(acc[r] + bias[e0 + r]);
            } else {
                f16x4 st;
                #pragma unroll
                for (int r = 0; r < 4; ++r)
                    st[r] = (_Float16)((acc[r] + bias[e0 + r]) * sc);
                _Float16* dst = (m == 0) ? Kb : Qb;
                *(f16x4*)&dst[(size_t)(b * N_ + n) * E_ + e0] = st;
            }
        }
        __syncthreads();   // Wl reuse barrier (and vT-complete barrier for m==2)
    }

    // cooperative V store in tiled layout: Vt[b][n/32][e][n%32]
    {
        const int e_s = t >> 3;            // 0..31
        const int nb  = t & 7;             // 0..7 (8 n's each)
        f16x8 v = *(const f16x8*)&vT[e_s][nb * 8];
        size_t base = ((size_t)(b * 128 + (n0 >> 5) + (nb >> 2)) * 32 + e_s) * 32
                    + (nb & 3) * 8;
        *(f16x8*)&Vt[base] = v;
    }
}

// ---------------------------------------------------------------------------
// Kernel 2 (R14): flash attention + fused output projection, j-tile 64.
// R13 post-mortem: prefetch was neutral; every pipe <20% busy at full
// occupancy; R12's +1 chain hop cost 50x its latency -> the limiter is L2
// REQUEST THROUGHPUT (each of 256 j-blocks/batch re-read all of K+V from
// L2; V loads were 16-segment 8KB-stride gathers). This version:
//  - 4 Q-columns per wave (j-tile 64/block): same K/V registers feed 4x the
//    MFMA work -> L2 traffic / 4. Grid 256 = 1 block/CU; 4-col ILP replaces
//    the lost TLP.
//  - V read from the tiled layout: 1KB-contiguous loads (8 line-requests,
//    was 16).
// Loop body per column is R10's PROVEN body (LDS P bounce + 2x independent
// 16x16x32 PV) + validated defer-rescale.
// ---------------------------------------------------------------------------
__global__ __launch_bounds__(512, 2) void attn_kernel(
    const _Float16* __restrict__ Qb, const _Float16* __restrict__ Kb,
    const _Float16* __restrict__ Vt, const _Float16* __restrict__ Wof16,
    const float* __restrict__ bo, const float* __restrict__ x,
    float* __restrict__ out)
{
    const int wave = threadIdx.x >> 6;     // i-split 0..7 (512 keys each)
    const int lane = threadIdx.x & 63;
    const int l15  = lane & 15, quad = lane >> 4;
    const int jg   = blockIdx.x;           // 0..255
    const int b    = jg >> 6;
    const int j0   = (jg & 63) << 6;       // j-tile of 64

    // per-wave, per-col 2176B regions: loop phase uses big[wave][0] as the
    // P bounce buffer; epilogue uses big[wave][cc] as osum[16][34] f32.
    __shared__ __align__(16) char big[8][4][2176];        // 69.6 KB
    __shared__ float    mls[8][2][4][16];                 // (m,l) per wave/col
    __shared__ _Float16 Om[4][16][40];                    // merged O rows

    _Float16 (*pb)[40] = (_Float16 (*)[40])(big[wave][0]);

    // Q B-frags for the 4 j-columns
    f16x8 Qf[4];
    #pragma unroll
    for (int cc = 0; cc < 4; ++cc)
        Qf[cc] = *(const f16x8*)(Qb + (size_t)(b * N_ + j0 + cc * 16 + l15) * E_ + quad * 8);

    f32x4 O0c[4], O1c[4];
    float mrow[4], lsum[4];
    #pragma unroll
    for (int cc = 0; cc < 4; ++cc) {
        O0c[cc] = (f32x4){0, 0, 0, 0}; O1c[cc] = (f32x4){0, 0, 0, 0};
        mrow[cc] = -1e30f; lsum[cc] = 0.f;
    }

    const _Float16* Kp = Kb + (size_t)b * N_ * E_ + (size_t)(wave << 9) * E_;
    // wave's 512 keys start at tile (b*128 + wave*16); 1024 f16 per 32-key tile
    const _Float16* Vp = Vt + ((size_t)(b * 128 + wave * 16) << 10);

    // prologue loads (it = 0)
    f16x8 K0 = *(const f16x8*)(Kp + (size_t)l15 * E_ + quad * 8);
    f16x8 K1 = *(const f16x8*)(Kp + (size_t)(16 + l15) * E_ + quad * 8);
    f16x8 Va = *(const f16x8*)(Vp + l15 * 32 + quad * 8);
    f16x8 Vc = *(const f16x8*)(Vp + (16 + l15) * 32 + quad * 8);

    for (int it = 0; it < 16; ++it) {
        const int i0n = ((it + 1) & 15) << 5;   // next tile (wraps; L2-hot)
        f32x4 S0[4], S1[4];
        f32x4 z = {0, 0, 0, 0};
        #pragma unroll
        for (int cc = 0; cc < 4; ++cc) {
            S0[cc] = __builtin_amdgcn_mfma_f32_16x16x32_f16(K0, Qf[cc], z, 0, 0, 0);
            S1[cc] = __builtin_amdgcn_mfma_f32_16x16x32_f16(K1, Qf[cc], z, 0, 0, 0);
        }
        // prefetch next iteration's K (same SSA names)
        K0 = *(const f16x8*)(Kp + (size_t)(i0n + l15) * E_ + quad * 8);
        K1 = *(const f16x8*)(Kp + (size_t)(i0n + 16 + l15) * E_ + quad * 8);

        #pragma unroll
        for (int cc = 0; cc < 4; ++cc) {
            float mx = fmaxf(
                fmaxf(fmaxf(S0[cc][0], S0[cc][1]), fmaxf(S0[cc][2], S0[cc][3])),
                fmaxf(fmaxf(S1[cc][0], S1[cc][1]), fmaxf(S1[cc][2], S1[cc][3])));
            mx = fmaxf(mx, __shfl_xor(mx, 16));
            mx = fmaxf(mx, __shfl_xor(mx, 32));
            if (__any(mx > mrow[cc] + 8.f)) {      // defer-rescale (THR=8)
                float mnew  = fmaxf(mrow[cc], mx);
                float alpha = exp2f(mrow[cc] - mnew);
                mrow[cc] = mnew;
                lsum[cc] *= alpha;
                O0c[cc] *= alpha;
                O1c[cc] *= alpha;
            }
            float m0 = mrow[cc];
            float p00 = exp2f(S0[cc][0] - m0), p01 = exp2f(S0[cc][1] - m0);
            float p02 = exp2f(S0[cc][2] - m0), p03 = exp2f(S0[cc][3] - m0);
            float p10 = exp2f(S1[cc][0] - m0), p11 = exp2f(S1[cc][1] - m0);
            float p12 = exp2f(S1[cc][2] - m0), p13 = exp2f(S1[cc][3] - m0);
            lsum[cc] += ((p00 + p01) + (p02 + p03)) + ((p10 + p11) + (p12 + p13));

            // P bounce (per-wave LDS; proven cheap — R12 lesson)
            f16x4 w0 = {(_Float16)p00, (_Float16)p01, (_Float16)p02, (_Float16)p03};
            f16x4 w1 = {(_Float16)p10, (_Float16)p11, (_Float16)p12, (_Float16)p13};
            *(f16x4*)&pb[l15][quad * 4]      = w0;
            *(f16x4*)&pb[l15][16 + quad * 4] = w1;
            f16x8 P = *(const f16x8*)&pb[l15][quad * 8];

            O0c[cc] = __builtin_amdgcn_mfma_f32_16x16x32_f16(Va, P, O0c[cc], 0, 0, 0);
            O1c[cc] = __builtin_amdgcn_mfma_f32_16x16x32_f16(Vc, P, O1c[cc], 0, 0, 0);
        }
        // prefetch next iteration's V (tiled layout: 1KB contiguous)
        Va = *(const f16x8*)(Vp + (i0n << 5) + l15 * 32 + quad * 8);
        Vc = *(const f16x8*)(Vp + (i0n << 5) + (16 + l15) * 32 + quad * 8);
    }

    // publish per-split (m, l) for all 4 cols
    #pragma unroll
    for (int cc = 0; cc < 4; ++cc) {
        float ls = lsum[cc];
        ls += __shfl_xor(ls, 16);
        ls += __shfl_xor(ls, 32);
        if (quad == 0) { mls[wave][0][cc][l15] = mrow[cc]; mls[wave][1][cc][l15] = ls; }
    }
    __syncthreads();

    // LSE combine + osum write, per col
    #pragma unroll
    for (int cc = 0; cc < 4; ++cc) {
        float M = -1e30f, ms[8], ls[8];
        #pragma unroll
        for (int s = 0; s < 8; ++s) {
            ms[s] = mls[s][0][cc][l15]; ls[s] = mls[s][1][cc][l15];
            M = fmaxf(M, ms[s]);
        }
        float L = 0.f;
        #pragma unroll
        for (int s = 0; s < 8; ++s) L += ls[s] * exp2f(ms[s] - M);
        const float w = exp2f(mrow[cc] - M) / L;
        float (*osum)[34] = (float (*)[34])(big[wave][cc]);
        *(f32x4*)&osum[l15][quad * 4]      = O0c[cc] * w;
        *(f32x4*)&osum[l15][16 + quad * 4] = O1c[cc] * w;
    }
    __syncthreads();

    // cross-split sum -> merged O rows (f16); one thread per (j, e), x4 cols
    {
        const int j = threadIdx.x >> 5;    // 0..15
        const int e = threadIdx.x & 31;    // 0..31
        #pragma unroll
        for (int cc = 0; cc < 4; ++cc) {
            float a = 0.f;
            #pragma unroll
            for (int s = 0; s < 8; ++s)
                a += ((const float (*)[34])(big[s][cc]))[j][e];
            Om[cc][j][e] = (_Float16)a;
        }
    }
    __syncthreads();

    // ---- fused output projection: each wave covers 32 channels x 4 cols ----
    f16x8 Bf2[4];
    #pragma unroll
    for (int cc = 0; cc < 4; ++cc)
        Bf2[cc] = *(const f16x8*)&Om[cc][l15][quad * 8];
    float* out_y = out + (size_t)b * C_ * N_;
    float* out_o = out + (size_t)B_ * C_ * N_ + (size_t)b * C_ * N_;
    const float* xb = x + (size_t)b * C_ * N_;
    #pragma unroll
    for (int ct = 0; ct < 2; ++ct) {
        const int c0 = wave * 32 + ct * 16;
        f16x8 Af = *(const f16x8*)(Wof16 + (size_t)(c0 + l15) * E_ + quad * 8);
        f32x4 acc[4];
        f32x4 z = {0, 0, 0, 0};
        #pragma unroll
        for (int cc = 0; cc < 4; ++cc)
            acc[cc] = __builtin_amdgcn_mfma_f32_16x16x32_f16(Af, Bf2[cc], z, 0, 0, 0);
        #pragma unroll
        for (int r = 0; r < 4; ++r) {
            const int c = c0 + quad * 4 + r;
            #pragma unroll
            for (int cc = 0; cc < 4; ++cc) {
                size_t idx = (size_t)c * N_ + j0 + cc * 16 + l15;
                float ov = acc[cc][r] + bo[c];
                out_o[idx] = ov;
                out_y[idx] = 0.5f * ov + xb[idx];
            }
        }
    }
}

// ---------------------------------------------------------------------------
extern "C" void kernel_launch(void* const* d_in, const int* in_sizes, int n_in,
                              void* d_out, int out_size, void* d_ws, size_t ws_size,
                              hipStream_t stream)
{
    const float* x  = (const float*)d_in[0];
    const float* Wk = (const float*)d_in[1];
    const float* bk = (const float*)d_in[2];
    const float* Wq = (const float*)d_in[3];
    const float* bq = (const float*)d_in[4];
    const float* Wv = (const float*)d_in[5];
    const float* bv = (const float*)d_in[6];
    const float* Wo = (const float*)d_in[7];
    const float* bo = (const float*)d_in[8];
    float* out = (float*)d_out;

    char* ws = (char*)d_ws;
    _Float16* Qb    = (_Float16*)(ws);                   // 1 MB  [B][N][E]
    _Float16* Kb    = (_Float16*)(ws + (1u << 20));      // 1 MB  [B][N][E]
    _Float16* Vt    = (_Float16*)(ws + (2u << 20));      // 1 MB  [B][N/32][E][32]
    _Float16* Wof16 = (_Float16*)(ws + (3u << 20));      // 16 KB [C][E]

    // 256 fused-projection blocks (x read ONCE) + 1 Wo-convert block
    proj_kernel<<<dim3(257), dim3(256), 0, stream>>>(
        x, Wk, bk, Wq, bq, Wv, bv, Wo, Qb, Kb, Vt, Wof16, out);
    // 256 blocks: j-tile 64, 1 block/CU
    attn_kernel<<<dim3(B_ * (N_ / 64)), dim3(512), 0, stream>>>(
        Qb, Kb, Vt, Wof16, bo, x, out);
}

// Round 6
// 131.729 us; speedup vs baseline: 1.3048x; 1.0395x over previous
//
#include <hip/hip_runtime.h>

#define B_ 4
#define C_ 256
#define N_ 4096
#define E_ 32

typedef _Float16 f16x8 __attribute__((ext_vector_type(8)));
typedef _Float16 f16x4 __attribute__((ext_vector_type(4)));
typedef float f32x4 __attribute__((ext_vector_type(4)));

#define LOG2E 1.44269504088896f

// LDS column swizzle: breaks bank conflicts of row-strided b128 reads while
// keeping 16B alignment (swizzle unit = 8 f16 = 16 B; same on write & read).
#define XSWZ(row, col) ((col) ^ ((((row) >> 2) & 7) << 3))

// ---------------------------------------------------------------------------
// Kernel 1 (unchanged from R14, passing): ONE block per x-tile computes all
// three projections; x staged once; V written in tiled layout
// Vt[b][n/32][e][n%32]. Block 256 converts Wo -> f16 and writes gamma.
// ---------------------------------------------------------------------------
__global__ __launch_bounds__(256) void proj_kernel(
    const float* __restrict__ x,
    const float* __restrict__ Wk, const float* __restrict__ bk,
    const float* __restrict__ Wq, const float* __restrict__ bq,
    const float* __restrict__ Wv, const float* __restrict__ bv,
    const float* __restrict__ Wo,
    _Float16* __restrict__ Qb, _Float16* __restrict__ Kb, _Float16* __restrict__ Vt,
    _Float16* __restrict__ Wof16, float* __restrict__ out)
{
    if (blockIdx.x == 256) {                 // Wo-convert + gamma (single block)
        for (int i4 = threadIdx.x; i4 < (C_ * E_) / 4; i4 += 256) {
            float4 wv = ((const float4*)Wo)[i4];
            f16x4 tp = {(_Float16)wv.x, (_Float16)wv.y, (_Float16)wv.z, (_Float16)wv.w};
            *(f16x4*)&Wof16[i4 * 4] = tp;
        }
        if (threadIdx.x == 0)
            out[(size_t)2 * B_ * C_ * N_] = 0.5f;   // gamma (non-learned)
        return;
    }
    const int b  = blockIdx.x >> 6;
    const int n0 = (blockIdx.x & 63) << 6;
    const int t    = threadIdx.x;
    const int lane = t & 63;
    const int wave = t >> 6;
    const int l15  = lane & 15;
    const int quad = lane >> 4;

    __shared__ _Float16 xT[64][264];   // x tile transposed [n_local][c], XSWZ'd
    __shared__ _Float16 Wl[32][264];   // current matrix's weights [e][c], XSWZ'd
    __shared__ _Float16 vT[32][72];    // V transpose staging [e][n_local]

    for (int i4 = t; i4 < (64 * 256) / 4; i4 += 256) {
        int j4 = (i4 & 15) * 4;
        int c  = i4 >> 4;
        float4 xv = *(const float4*)(x + (size_t)(b * C_ + c) * N_ + n0 + j4);
        xT[j4 + 0][XSWZ(j4 + 0, c)] = (_Float16)xv.x;
        xT[j4 + 1][XSWZ(j4 + 1, c)] = (_Float16)xv.y;
        xT[j4 + 2][XSWZ(j4 + 2, c)] = (_Float16)xv.z;
        xT[j4 + 3][XSWZ(j4 + 3, c)] = (_Float16)xv.w;
    }

    const float* Ws[3] = {Wk, Wq, Wv};
    const float* bs[3] = {bk, bq, bv};

    const int row = wave * 16 + l15;
    f16x8 Bf[8];

    for (int m = 0; m < 3; ++m) {
        for (int i4 = t; i4 < (E_ * C_) / 4; i4 += 256) {
            float4 wv = ((const float4*)Ws[m])[i4];
            int e = (i4 * 4) >> 8, c = (i4 * 4) & 255;
            f16x4 tp = {(_Float16)wv.x, (_Float16)wv.y, (_Float16)wv.z, (_Float16)wv.w};
            *(f16x4*)&Wl[e][XSWZ(e, c)] = tp;
        }
        __syncthreads();
        if (m == 0) {
            #pragma unroll
            for (int kk = 0; kk < 8; ++kk)
                Bf[kk] = *(const f16x8*)&xT[row][XSWZ(row, kk * 32 + quad * 8)];
        }
        const float sc = (m == 1) ? LOG2E : 1.0f;
        const float* bias = bs[m];
        #pragma unroll
        for (int et = 0; et < 2; ++et) {
            f32x4 acc = {0.f, 0.f, 0.f, 0.f};
            #pragma unroll
            for (int kk = 0; kk < 8; ++kk) {
                const int e = et * 16 + l15;
                f16x8 Af = *(const f16x8*)&Wl[e][XSWZ(e, kk * 32 + quad * 8)];
                acc = __builtin_amdgcn_mfma_f32_16x16x32_f16(Af, Bf[kk], acc, 0, 0, 0);
            }
            const int n  = n0 + wave * 16 + l15;
            const int e0 = et * 16 + quad * 4;
            if (m == 2) {
                #pragma unroll
                for (int r = 0; r < 4; ++r)
                    vT[e0 + r][wave * 16 + l15] = (_Float16)(acc[r] + bias[e0 + r]);
            } else {
                f16x4 st;
                #pragma unroll
                for (int r = 0; r < 4; ++r)
                    st[r] = (_Float16)((acc[r] + bias[e0 + r]) * sc);
                _Float16* dst = (m == 0) ? Kb : Qb;
                *(f16x4*)&dst[(size_t)(b * N_ + n) * E_ + e0] = st;
            }
        }
        __syncthreads();
    }

    // cooperative V store in tiled layout: Vt[b][n/32][e][n%32]
    {
        const int e_s = t >> 3;            // 0..31
        const int nb  = t & 7;             // 0..7 (8 n's each)
        f16x8 v = *(const f16x8*)&vT[e_s][nb * 8];
        size_t base = ((size_t)(b * 128 + (n0 >> 5) + (nb >> 2)) * 32 + e_s) * 32
                    + (nb & 3) * 8;
        *(f16x8*)&Vt[base] = v;
    }
}

// ---------------------------------------------------------------------------
// Kernel 2 (R15): flash attention + fused output projection, j-tile 32.
// R14 post-mortem: traffic/4 worked but occupancy collapsed (17.6%) and the
// gains cancelled — the kernel is chain-latency-bound per wave and
// throughput = waves_per_SIMD / chain_length. R15 rebalances:
//  - 2 cols/wave, grid 512, 2 blocks/CU (16 waves/CU): 2x waves/SIMD at
//    only 2x the (non-binding) L2 traffic of R14.
//  - shfl-free common path: __any(per-lane max > mrow+8) is the SAME truth
//    value as the reduced-max check (any over 64 lanes covers all quads);
//    the 2 cross-lane shuffles move inside the rare trigger branch.
//  - per-column P-bounce buffers + phase split (softmax+writes both cols,
//    then reads+MFMAs both cols): the two ~120cyc ds_read latencies overlap.
// ---------------------------------------------------------------------------
__global__ __launch_bounds__(512, 4) void attn_kernel(
    const _Float16* __restrict__ Qb, const _Float16* __restrict__ Kb,
    const _Float16* __restrict__ Vt, const _Float16* __restrict__ Wof16,
    const float* __restrict__ bo, const float* __restrict__ x,
    float* __restrict__ out)
{
    const int wave = threadIdx.x >> 6;     // i-split 0..7 (512 keys each)
    const int lane = threadIdx.x & 63;
    const int l15  = lane & 15, quad = lane >> 4;
    const int jg   = blockIdx.x;           // 0..511
    const int b    = jg >> 7;
    const int j0   = (jg & 127) << 5;      // j-tile of 32

    // per-wave, per-col 2176B regions: loop phase = P bounce buffers;
    // epilogue = osum[16][34] f32 overlay (barrier-separated).
    __shared__ __align__(16) char big[8][2][2176];        // 34.8 KB
    __shared__ float    mls[8][2][2][16];                 // 4 KB
    __shared__ _Float16 Om[2][16][40];                    // 2.5 KB

    // Q B-frags for the 2 j-columns
    f16x8 Qf[2];
    #pragma unroll
    for (int cc = 0; cc < 2; ++cc)
        Qf[cc] = *(const f16x8*)(Qb + (size_t)(b * N_ + j0 + cc * 16 + l15) * E_ + quad * 8);

    f32x4 O0c[2], O1c[2];
    float mrow[2], lsum[2];
    #pragma unroll
    for (int cc = 0; cc < 2; ++cc) {
        O0c[cc] = (f32x4){0, 0, 0, 0}; O1c[cc] = (f32x4){0, 0, 0, 0};
        mrow[cc] = -1e30f; lsum[cc] = 0.f;
    }

    const _Float16* Kp = Kb + (size_t)b * N_ * E_ + (size_t)(wave << 9) * E_;
    const _Float16* Vp = Vt + ((size_t)(b * 128 + wave * 16) << 10);

    // prologue loads (it = 0)
    f16x8 K0 = *(const f16x8*)(Kp + (size_t)l15 * E_ + quad * 8);
    f16x8 K1 = *(const f16x8*)(Kp + (size_t)(16 + l15) * E_ + quad * 8);
    f16x8 Va = *(const f16x8*)(Vp + l15 * 32 + quad * 8);
    f16x8 Vc = *(const f16x8*)(Vp + (16 + l15) * 32 + quad * 8);

    for (int it = 0; it < 16; ++it) {
        const int i0n = ((it + 1) & 15) << 5;   // next tile (wraps; L2-hot)
        f32x4 S0[2], S1[2];
        f32x4 z = {0, 0, 0, 0};
        #pragma unroll
        for (int cc = 0; cc < 2; ++cc) {
            S0[cc] = __builtin_amdgcn_mfma_f32_16x16x32_f16(K0, Qf[cc], z, 0, 0, 0);
            S1[cc] = __builtin_amdgcn_mfma_f32_16x16x32_f16(K1, Qf[cc], z, 0, 0, 0);
        }
        // prefetch next iteration's K (same SSA names)
        K0 = *(const f16x8*)(Kp + (size_t)(i0n + l15) * E_ + quad * 8);
        K1 = *(const f16x8*)(Kp + (size_t)(i0n + 16 + l15) * E_ + quad * 8);

        // ---- phase A: softmax for both cols, P writes to per-col buffers ----
        #pragma unroll
        for (int cc = 0; cc < 2; ++cc) {
            // per-lane max only (7 fmax, NO cross-lane ops on common path)
            float mxl = fmaxf(
                fmaxf(fmaxf(S0[cc][0], S0[cc][1]), fmaxf(S0[cc][2], S0[cc][3])),
                fmaxf(fmaxf(S1[cc][0], S1[cc][1]), fmaxf(S1[cc][2], S1[cc][3])));
            if (__any(mxl > mrow[cc] + 8.f)) {     // trigger: full reduce+rescale
                float mx = fmaxf(mxl, __shfl_xor(mxl, 16));
                mx = fmaxf(mx, __shfl_xor(mx, 32));
                float mnew  = fmaxf(mrow[cc], mx);
                float alpha = exp2f(mrow[cc] - mnew);
                mrow[cc] = mnew;
                lsum[cc] *= alpha;
                O0c[cc] *= alpha;
                O1c[cc] *= alpha;
            }
            float m0 = mrow[cc];
            float p00 = exp2f(S0[cc][0] - m0), p01 = exp2f(S0[cc][1] - m0);
            float p02 = exp2f(S0[cc][2] - m0), p03 = exp2f(S0[cc][3] - m0);
            float p10 = exp2f(S1[cc][0] - m0), p11 = exp2f(S1[cc][1] - m0);
            float p12 = exp2f(S1[cc][2] - m0), p13 = exp2f(S1[cc][3] - m0);
            lsum[cc] += ((p00 + p01) + (p02 + p03)) + ((p10 + p11) + (p12 + p13));

            f16x4 w0 = {(_Float16)p00, (_Float16)p01, (_Float16)p02, (_Float16)p03};
            f16x4 w1 = {(_Float16)p10, (_Float16)p11, (_Float16)p12, (_Float16)p13};
            _Float16 (*pb)[40] = (_Float16 (*)[40])(big[wave][cc]);
            *(f16x4*)&pb[l15][quad * 4]      = w0;
            *(f16x4*)&pb[l15][16 + quad * 4] = w1;
        }
        // ---- phase B: P reads + PV MFMAs (the two read latencies overlap) ----
        #pragma unroll
        for (int cc = 0; cc < 2; ++cc) {
            _Float16 (*pb)[40] = (_Float16 (*)[40])(big[wave][cc]);
            f16x8 P = *(const f16x8*)&pb[l15][quad * 8];
            O0c[cc] = __builtin_amdgcn_mfma_f32_16x16x32_f16(Va, P, O0c[cc], 0, 0, 0);
            O1c[cc] = __builtin_amdgcn_mfma_f32_16x16x32_f16(Vc, P, O1c[cc], 0, 0, 0);
        }
        // prefetch next iteration's V (tiled layout: 1KB contiguous)
        Va = *(const f16x8*)(Vp + (i0n << 5) + l15 * 32 + quad * 8);
        Vc = *(const f16x8*)(Vp + (i0n << 5) + (16 + l15) * 32 + quad * 8);
    }

    // publish per-split (m, l) for both cols
    #pragma unroll
    for (int cc = 0; cc < 2; ++cc) {
        float ls = lsum[cc];
        ls += __shfl_xor(ls, 16);
        ls += __shfl_xor(ls, 32);
        if (quad == 0) { mls[wave][0][cc][l15] = mrow[cc]; mls[wave][1][cc][l15] = ls; }
    }
    __syncthreads();

    // LSE combine + osum write, per col
    #pragma unroll
    for (int cc = 0; cc < 2; ++cc) {
        float M = -1e30f, ms[8], ls[8];
        #pragma unroll
        for (int s = 0; s < 8; ++s) {
            ms[s] = mls[s][0][cc][l15]; ls[s] = mls[s][1][cc][l15];
            M = fmaxf(M, ms[s]);
        }
        float L = 0.f;
        #pragma unroll
        for (int s = 0; s < 8; ++s) L += ls[s] * exp2f(ms[s] - M);
        const float w = exp2f(mrow[cc] - M) / L;
        float (*osum)[34] = (float (*)[34])(big[wave][cc]);
        *(f32x4*)&osum[l15][quad * 4]      = O0c[cc] * w;
        *(f32x4*)&osum[l15][16 + quad * 4] = O1c[cc] * w;
    }
    __syncthreads();

    // cross-split sum -> merged O rows (f16); one thread per (j, e), x2 cols
    {
        const int j = threadIdx.x >> 5;    // 0..15
        const int e = threadIdx.x & 31;    // 0..31
        #pragma unroll
        for (int cc = 0; cc < 2; ++cc) {
            float a = 0.f;
            #pragma unroll
            for (int s = 0; s < 8; ++s)
                a += ((const float (*)[34])(big[s][cc]))[j][e];
            Om[cc][j][e] = (_Float16)a;
        }
    }
    __syncthreads();

    // ---- fused output projection: each wave covers 32 channels x 2 cols ----
    f16x8 Bf2[2];
    #pragma unroll
    for (int cc = 0; cc < 2; ++cc)
        Bf2[cc] = *(const f16x8*)&Om[cc][l15][quad * 8];
    float* out_y = out + (size_t)b * C_ * N_;
    float* out_o = out + (size_t)B_ * C_ * N_ + (size_t)b * C_ * N_;
    const float* xb = x + (size_t)b * C_ * N_;
    #pragma unroll
    for (int ct = 0; ct < 2; ++ct) {
        const int c0 = wave * 32 + ct * 16;
        f16x8 Af = *(const f16x8*)(Wof16 + (size_t)(c0 + l15) * E_ + quad * 8);
        f32x4 acc[2];
        f32x4 z = {0, 0, 0, 0};
        #pragma unroll
        for (int cc = 0; cc < 2; ++cc)
            acc[cc] = __builtin_amdgcn_mfma_f32_16x16x32_f16(Af, Bf2[cc], z, 0, 0, 0);
        #pragma unroll
        for (int r = 0; r < 4; ++r) {
            const int c = c0 + quad * 4 + r;
            #pragma unroll
            for (int cc = 0; cc < 2; ++cc) {
                size_t idx = (size_t)c * N_ + j0 + cc * 16 + l15;
                float ov = acc[cc][r] + bo[c];
                out_o[idx] = ov;
                out_y[idx] = 0.5f * ov + xb[idx];
            }
        }
    }
}

// ---------------------------------------------------------------------------
extern "C" void kernel_launch(void* const* d_in, const int* in_sizes, int n_in,
                              void* d_out, int out_size, void* d_ws, size_t ws_size,
                              hipStream_t stream)
{
    const float* x  = (const float*)d_in[0];
    const float* Wk = (const float*)d_in[1];
    const float* bk = (const float*)d_in[2];
    const float* Wq = (const float*)d_in[3];
    const float* bq = (const float*)d_in[4];
    const float* Wv = (const float*)d_in[5];
    const float* bv = (const float*)d_in[6];
    const float* Wo = (const float*)d_in[7];
    const float* bo = (const float*)d_in[8];
    float* out = (float*)d_out;

    char* ws = (char*)d_ws;
    _Float16* Qb    = (_Float16*)(ws);                   // 1 MB  [B][N][E]
    _Float16* Kb    = (_Float16*)(ws + (1u << 20));      // 1 MB  [B][N][E]
    _Float16* Vt    = (_Float16*)(ws + (2u << 20));      // 1 MB  [B][N/32][E][32]
    _Float16* Wof16 = (_Float16*)(ws + (3u << 20));      // 16 KB [C][E]

    // 256 fused-projection blocks (x read ONCE) + 1 Wo-convert block
    proj_kernel<<<dim3(257), dim3(256), 0, stream>>>(
        x, Wk, bk, Wq, bq, Wv, bv, Wo, Qb, Kb, Vt, Wof16, out);
    // 512 blocks: j-tile 32, 2 blocks/CU (16 waves/CU)
    attn_kernel<<<dim3(B_ * (N_ / 32)), dim3(512), 0, stream>>>(
        Qb, Kb, Vt, Wof16, bo, x, out);
}

// Round 8
// 124.627 us; speedup vs baseline: 1.3791x; 1.0570x over previous
//
#include <hip/hip_runtime.h>

#define B_ 4
#define C_ 256
#define N_ 4096
#define E_ 32

typedef _Float16 f16x8 __attribute__((ext_vector_type(8)));
typedef _Float16 f16x4 __attribute__((ext_vector_type(4)));
typedef _Float16 f16x2 __attribute__((ext_vector_type(2)));
typedef float f32x4 __attribute__((ext_vector_type(4)));

#define LOG2E 1.44269504088896f
#define EXP2(x) __builtin_amdgcn_exp2f(x)
// cvt_pkrtz returns __fp16x2; bit-identical to f16x2 — bit_cast is free
#define PKRTZ(a, b) __builtin_bit_cast(f16x2, __builtin_amdgcn_cvt_pkrtz((a), (b)))

// LDS column swizzle: breaks bank conflicts of row-strided b128 reads while
// keeping 16B alignment (swizzle unit = 8 f16 = 16 B; same on write & read).
#define XSWZ(row, col) ((col) ^ ((((row) >> 2) & 7) << 3))

// ---------------------------------------------------------------------------
// Kernel 1 (R16): one block per x-tile computes all three projections; x
// staged once; V written in tiled layout Vt[b][n/32][e][n%32].
// Wo-convert distributed one row per block (grid exactly 256 -> no straggler).
// ---------------------------------------------------------------------------
__global__ __launch_bounds__(256) void proj_kernel(
    const float* __restrict__ x,
    const float* __restrict__ Wk, const float* __restrict__ bk,
    const float* __restrict__ Wq, const float* __restrict__ bq,
    const float* __restrict__ Wv, const float* __restrict__ bv,
    const float* __restrict__ Wo,
    _Float16* __restrict__ Qb, _Float16* __restrict__ Kb, _Float16* __restrict__ Vt,
    _Float16* __restrict__ Wof16, float* __restrict__ out)
{
    const int b  = blockIdx.x >> 6;
    const int n0 = (blockIdx.x & 63) << 6;
    const int t    = threadIdx.x;
    const int lane = t & 63;
    const int wave = t >> 6;
    const int l15  = lane & 15;
    const int quad = lane >> 4;

    // distributed Wo convert: this block converts Wo row c = blockIdx.x
    if (t < 8) {
        float4 wv = ((const float4*)(Wo + blockIdx.x * E_))[t];
        f16x4 tp = {(_Float16)wv.x, (_Float16)wv.y, (_Float16)wv.z, (_Float16)wv.w};
        *(f16x4*)&Wof16[blockIdx.x * E_ + t * 4] = tp;
    }
    if (blockIdx.x == 0 && t == 0)
        out[(size_t)2 * B_ * C_ * N_] = 0.5f;   // gamma (non-learned)

    __shared__ _Float16 xT[64][264];   // x tile transposed [n_local][c], XSWZ'd
    __shared__ _Float16 Wl[32][264];   // current matrix's weights [e][c], XSWZ'd
    __shared__ _Float16 vT[32][72];    // V transpose staging [e][n_local]

    for (int i4 = t; i4 < (64 * 256) / 4; i4 += 256) {
        int j4 = (i4 & 15) * 4;
        int c  = i4 >> 4;
        float4 xv = *(const float4*)(x + (size_t)(b * C_ + c) * N_ + n0 + j4);
        xT[j4 + 0][XSWZ(j4 + 0, c)] = (_Float16)xv.x;
        xT[j4 + 1][XSWZ(j4 + 1, c)] = (_Float16)xv.y;
        xT[j4 + 2][XSWZ(j4 + 2, c)] = (_Float16)xv.z;
        xT[j4 + 3][XSWZ(j4 + 3, c)] = (_Float16)xv.w;
    }

    const float* Ws[3] = {Wk, Wq, Wv};
    const float* bs[3] = {bk, bq, bv};

    const int row = wave * 16 + l15;
    f16x8 Bf[8];

    for (int m = 0; m < 3; ++m) {
        for (int i4 = t; i4 < (E_ * C_) / 4; i4 += 256) {
            float4 wv = ((const float4*)Ws[m])[i4];
            int e = (i4 * 4) >> 8, c = (i4 * 4) & 255;
            f16x4 tp = {(_Float16)wv.x, (_Float16)wv.y, (_Float16)wv.z, (_Float16)wv.w};
            *(f16x4*)&Wl[e][XSWZ(e, c)] = tp;
        }
        __syncthreads();
        if (m == 0) {
            #pragma unroll
            for (int kk = 0; kk < 8; ++kk)
                Bf[kk] = *(const f16x8*)&xT[row][XSWZ(row, kk * 32 + quad * 8)];
        }
        const float sc = (m == 1) ? LOG2E : 1.0f;
        const float* bias = bs[m];
        #pragma unroll
        for (int et = 0; et < 2; ++et) {
            f32x4 acc = {0.f, 0.f, 0.f, 0.f};
            #pragma unroll
            for (int kk = 0; kk < 8; ++kk) {
                const int e = et * 16 + l15;
                f16x8 Af = *(const f16x8*)&Wl[e][XSWZ(e, kk * 32 + quad * 8)];
                acc = __builtin_amdgcn_mfma_f32_16x16x32_f16(Af, Bf[kk], acc, 0, 0, 0);
            }
            const int n  = n0 + wave * 16 + l15;
            const int e0 = et * 16 + quad * 4;
            if (m == 2) {
                #pragma unroll
                for (int r = 0; r < 4; ++r)
                    vT[e0 + r][wave * 16 + l15] = (_Float16)(acc[r] + bias[e0 + r]);
            } else {
                f16x4 st;
                #pragma unroll
                for (int r = 0; r < 4; ++r)
                    st[r] = (_Float16)((acc[r] + bias[e0 + r]) * sc);
                _Float16* dst = (m == 0) ? Kb : Qb;
                *(f16x4*)&dst[(size_t)(b * N_ + n) * E_ + e0] = st;
            }
        }
        __syncthreads();
    }

    // cooperative V store in tiled layout: Vt[b][n/32][e][n%32]
    {
        const int e_s = t >> 3;            // 0..31
        const int nb  = t & 7;             // 0..7 (8 n's each)
        f16x8 v = *(const f16x8*)&vT[e_s][nb * 8];
        size_t base = ((size_t)(b * 128 + (n0 >> 5) + (nb >> 2)) * 32 + e_s) * 32
                    + (nb & 3) * 8;
        *(f16x8*)&Vt[base] = v;
    }
}

// ---------------------------------------------------------------------------
// Kernel 2 (R16 fixed): flash attention + fused output projection, j-tile 32.
// VALU-volume cuts: bare v_exp_f32, pkrtz P-packing (bit_cast fixes the
// __fp16x2 -> f16x2 type mismatch), max3-shaped fmax tree, affine prefetch
// addresses + unroll 2, s_setprio around MFMA clusters.
// ---------------------------------------------------------------------------
__global__ __launch_bounds__(512, 4) void attn_kernel(
    const _Float16* __restrict__ Qb, const _Float16* __restrict__ Kb,
    const _Float16* __restrict__ Vt, const _Float16* __restrict__ Wof16,
    const float* __restrict__ bo, const float* __restrict__ x,
    float* __restrict__ out)
{
    const int wave = threadIdx.x >> 6;     // i-split 0..7 (512 keys each)
    const int lane = threadIdx.x & 63;
    const int l15  = lane & 15, quad = lane >> 4;
    const int jg   = blockIdx.x;           // 0..511
    const int b    = jg >> 7;
    const int j0   = (jg & 127) << 5;      // j-tile of 32

    __shared__ __align__(16) char big[8][2][2176];        // 34.8 KB
    __shared__ float    mls[8][2][2][16];
    __shared__ _Float16 Om[2][16][40];

    f16x8 Qf[2];
    #pragma unroll
    for (int cc = 0; cc < 2; ++cc)
        Qf[cc] = *(const f16x8*)(Qb + (size_t)(b * N_ + j0 + cc * 16 + l15) * E_ + quad * 8);

    f32x4 O0c[2], O1c[2];
    float mrow[2], lsum[2];
    #pragma unroll
    for (int cc = 0; cc < 2; ++cc) {
        O0c[cc] = (f32x4){0, 0, 0, 0}; O1c[cc] = (f32x4){0, 0, 0, 0};
        mrow[cc] = -1e30f; lsum[cc] = 0.f;
    }

    const _Float16* Kp = Kb + (size_t)b * N_ * E_ + (size_t)(wave << 9) * E_;
    const _Float16* Vp = Vt + ((size_t)(b * 128 + wave * 16) << 10);

    // prologue loads (it = 0)
    f16x8 K0 = *(const f16x8*)(Kp + (size_t)l15 * E_ + quad * 8);
    f16x8 K1 = *(const f16x8*)(Kp + (size_t)(16 + l15) * E_ + quad * 8);
    f16x8 Va = *(const f16x8*)(Vp + l15 * 32 + quad * 8);
    f16x8 Vc = *(const f16x8*)(Vp + (16 + l15) * 32 + quad * 8);

    #pragma unroll 2
    for (int it = 0; it < 16; ++it) {
        const int i0n = (it + 1) << 5;    // affine (no wrap): it=15 over-read
                                          // stays inside the 256MiB ws, unused
        f32x4 S0[2], S1[2];
        f32x4 z = {0, 0, 0, 0};
        __builtin_amdgcn_s_setprio(1);
        #pragma unroll
        for (int cc = 0; cc < 2; ++cc) {
            S0[cc] = __builtin_amdgcn_mfma_f32_16x16x32_f16(K0, Qf[cc], z, 0, 0, 0);
            S1[cc] = __builtin_amdgcn_mfma_f32_16x16x32_f16(K1, Qf[cc], z, 0, 0, 0);
        }
        __builtin_amdgcn_s_setprio(0);
        // prefetch next iteration's K (same SSA names)
        K0 = *(const f16x8*)(Kp + (size_t)(i0n + l15) * E_ + quad * 8);
        K1 = *(const f16x8*)(Kp + (size_t)(i0n + 16 + l15) * E_ + quad * 8);

        // ---- phase A: softmax for both cols, P writes to per-col buffers ----
        #pragma unroll
        for (int cc = 0; cc < 2; ++cc) {
            // per-lane max, max3-shaped; no cross-lane on common path
            float mxa = fmaxf(fmaxf(S0[cc][0], S0[cc][1]), S0[cc][2]);
            float mxb = fmaxf(fmaxf(S0[cc][3], S1[cc][0]), S1[cc][1]);
            float mxc = fmaxf(fmaxf(S1[cc][2], S1[cc][3]), mxa);
            float mxl = fmaxf(mxb, mxc);
            if (__any(mxl > mrow[cc] + 8.f)) {     // trigger: reduce + rescale
                float mx = fmaxf(mxl, __shfl_xor(mxl, 16));
                mx = fmaxf(mx, __shfl_xor(mx, 32));
                float mnew  = fmaxf(mrow[cc], mx);
                float alpha = EXP2(mrow[cc] - mnew);
                mrow[cc] = mnew;
                lsum[cc] *= alpha;
                O0c[cc] *= alpha;
                O1c[cc] *= alpha;
            }
            float m0 = mrow[cc];
            float p00 = EXP2(S0[cc][0] - m0), p01 = EXP2(S0[cc][1] - m0);
            float p02 = EXP2(S0[cc][2] - m0), p03 = EXP2(S0[cc][3] - m0);
            float p10 = EXP2(S1[cc][0] - m0), p11 = EXP2(S1[cc][1] - m0);
            float p12 = EXP2(S1[cc][2] - m0), p13 = EXP2(S1[cc][3] - m0);
            lsum[cc] += ((p00 + p01) + (p02 + p03)) + ((p10 + p11) + (p12 + p13));

            // pack via v_cvt_pkrtz_f16_f32 (1 instr per f32 pair)
            f16x2 a0 = PKRTZ(p00, p01);
            f16x2 a1 = PKRTZ(p02, p03);
            f16x2 a2 = PKRTZ(p10, p11);
            f16x2 a3 = PKRTZ(p12, p13);
            f16x4 w0 = {a0[0], a0[1], a1[0], a1[1]};
            f16x4 w1 = {a2[0], a2[1], a3[0], a3[1]};
            _Float16 (*pb)[40] = (_Float16 (*)[40])(big[wave][cc]);
            *(f16x4*)&pb[l15][quad * 4]      = w0;
            *(f16x4*)&pb[l15][16 + quad * 4] = w1;
        }
        // ---- phase B: P reads + PV MFMAs (read latencies overlap) ----
        f16x8 P0, P1;
        {
            _Float16 (*pb0)[40] = (_Float16 (*)[40])(big[wave][0]);
            _Float16 (*pb1)[40] = (_Float16 (*)[40])(big[wave][1]);
            P0 = *(const f16x8*)&pb0[l15][quad * 8];
            P1 = *(const f16x8*)&pb1[l15][quad * 8];
        }
        __builtin_amdgcn_s_setprio(1);
        O0c[0] = __builtin_amdgcn_mfma_f32_16x16x32_f16(Va, P0, O0c[0], 0, 0, 0);
        O1c[0] = __builtin_amdgcn_mfma_f32_16x16x32_f16(Vc, P0, O1c[0], 0, 0, 0);
        O0c[1] = __builtin_amdgcn_mfma_f32_16x16x32_f16(Va, P1, O0c[1], 0, 0, 0);
        O1c[1] = __builtin_amdgcn_mfma_f32_16x16x32_f16(Vc, P1, O1c[1], 0, 0, 0);
        __builtin_amdgcn_s_setprio(0);
        // prefetch next iteration's V (tiled layout: 1KB contiguous)
        Va = *(const f16x8*)(Vp + (i0n << 5) + l15 * 32 + quad * 8);
        Vc = *(const f16x8*)(Vp + (i0n << 5) + (16 + l15) * 32 + quad * 8);
    }

    // publish per-split (m, l) for both cols
    #pragma unroll
    for (int cc = 0; cc < 2; ++cc) {
        float ls = lsum[cc];
        ls += __shfl_xor(ls, 16);
        ls += __shfl_xor(ls, 32);
        if (quad == 0) { mls[wave][0][cc][l15] = mrow[cc]; mls[wave][1][cc][l15] = ls; }
    }
    __syncthreads();

    // LSE combine + osum write, per col
    #pragma unroll
    for (int cc = 0; cc < 2; ++cc) {
        float M = -1e30f, ms[8], ls[8];
        #pragma unroll
        for (int s = 0; s < 8; ++s) {
            ms[s] = mls[s][0][cc][l15]; ls[s] = mls[s][1][cc][l15];
            M = fmaxf(M, ms[s]);
        }
        float L = 0.f;
        #pragma unroll
        for (int s = 0; s < 8; ++s) L += ls[s] * EXP2(ms[s] - M);
        const float w = EXP2(mrow[cc] - M) / L;
        float (*osum)[34] = (float (*)[34])(big[wave][cc]);
        *(f32x4*)&osum[l15][quad * 4]      = O0c[cc] * w;
        *(f32x4*)&osum[l15][16 + quad * 4] = O1c[cc] * w;
    }
    __syncthreads();

    // cross-split sum -> merged O rows (f16); one thread per (j, e), x2 cols
    {
        const int j = threadIdx.x >> 5;    // 0..15
        const int e = threadIdx.x & 31;    // 0..31
        #pragma unroll
        for (int cc = 0; cc < 2; ++cc) {
            float a = 0.f;
            #pragma unroll
            for (int s = 0; s < 8; ++s)
                a += ((const float (*)[34])(big[s][cc]))[j][e];
            Om[cc][j][e] = (_Float16)a;
        }
    }
    __syncthreads();

    // ---- fused output projection: each wave covers 32 channels x 2 cols ----
    f16x8 Bf2[2];
    #pragma unroll
    for (int cc = 0; cc < 2; ++cc)
        Bf2[cc] = *(const f16x8*)&Om[cc][l15][quad * 8];
    float* out_y = out + (size_t)b * C_ * N_;
    float* out_o = out + (size_t)B_ * C_ * N_ + (size_t)b * C_ * N_;
    const float* xb = x + (size_t)b * C_ * N_;
    #pragma unroll
    for (int ct = 0; ct < 2; ++ct) {
        const int c0 = wave * 32 + ct * 16;
        f16x8 Af = *(const f16x8*)(Wof16 + (size_t)(c0 + l15) * E_ + quad * 8);
        f32x4 acc[2];
        f32x4 z = {0, 0, 0, 0};
        #pragma unroll
        for (int cc = 0; cc < 2; ++cc)
            acc[cc] = __builtin_amdgcn_mfma_f32_16x16x32_f16(Af, Bf2[cc], z, 0, 0, 0);
        #pragma unroll
        for (int r = 0; r < 4; ++r) {
            const int c = c0 + quad * 4 + r;
            #pragma unroll
            for (int cc = 0; cc < 2; ++cc) {
                size_t idx = (size_t)c * N_ + j0 + cc * 16 + l15;
                float ov = acc[cc][r] + bo[c];
                out_o[idx] = ov;
                out_y[idx] = 0.5f * ov + xb[idx];
            }
        }
    }
}

// ---------------------------------------------------------------------------
extern "C" void kernel_launch(void* const* d_in, const int* in_sizes, int n_in,
                              void* d_out, int out_size, void* d_ws, size_t ws_size,
                              hipStream_t stream)
{
    const float* x  = (const float*)d_in[0];
    const float* Wk = (const float*)d_in[1];
    const float* bk = (const float*)d_in[2];
    const float* Wq = (const float*)d_in[3];
    const float* bq = (const float*)d_in[4];
    const float* Wv = (const float*)d_in[5];
    const float* bv = (const float*)d_in[6];
    const float* Wo = (const float*)d_in[7];
    const float* bo = (const float*)d_in[8];
    float* out = (float*)d_out;

    char* ws = (char*)d_ws;
    _Float16* Qb    = (_Float16*)(ws);                   // 1 MB  [B][N][E]
    _Float16* Kb    = (_Float16*)(ws + (1u << 20));      // 1 MB  [B][N][E]
    _Float16* Vt    = (_Float16*)(ws + (2u << 20));      // 1 MB  [B][N/32][E][32]
    _Float16* Wof16 = (_Float16*)(ws + (3u << 20));      // 16 KB [C][E]

    // 256 fused-projection blocks (x read once; Wo row per block)
    proj_kernel<<<dim3(256), dim3(256), 0, stream>>>(
        x, Wk, bk, Wq, bq, Wv, bv, Wo, Qb, Kb, Vt, Wof16, out);
    // 512 blocks: j-tile 32, 2 blocks/CU (16 waves/CU)
    attn_kernel<<<dim3(B_ * (N_ / 32)), dim3(512), 0, stream>>>(
        Qb, Kb, Vt, Wof16, bo, x, out);
}

// Round 9
// 122.817 us; speedup vs baseline: 1.3995x; 1.0147x over previous
//
#include <hip/hip_runtime.h>

#define B_ 4
#define C_ 256
#define N_ 4096
#define E_ 32

typedef _Float16 f16x8 __attribute__((ext_vector_type(8)));
typedef _Float16 f16x4 __attribute__((ext_vector_type(4)));
typedef _Float16 f16x2 __attribute__((ext_vector_type(2)));
typedef float f32x4 __attribute__((ext_vector_type(4)));

#define LOG2E 1.44269504088896f
#define EXP2(x) __builtin_amdgcn_exp2f(x)
// cvt_pkrtz returns __fp16x2; bit-identical to f16x2 — bit_cast is free
#define PKRTZ(a, b) __builtin_bit_cast(f16x2, __builtin_amdgcn_cvt_pkrtz((a), (b)))

// LDS column swizzle: breaks bank conflicts of row-strided b128 reads while
// keeping 16B alignment (swizzle unit = 8 f16 = 16 B; same on write & read).
#define XSWZ(row, col) ((col) ^ ((((row) >> 2) & 7) << 3))

// ---------------------------------------------------------------------------
// Kernel 1 (R17): proj restructured for occupancy — 512 blocks x 256 thr,
// n-tile 32, 2 blocks/CU (was 256 blocks = 1 block/CU, 4 waves/CU total:
// every weight-stage latency and barrier fully exposed). Wave decomp:
// rowg = wave>>1 (n half), et = wave&1 (e half); 8 MFMAs/wave/matrix.
// x staged once; V written in tiled layout Vt[b][n/32][e][n%32] (exactly
// one 2KB tile per block). Wo-convert distributed over blocks 0..255.
// ---------------------------------------------------------------------------
__global__ __launch_bounds__(256) void proj_kernel(
    const float* __restrict__ x,
    const float* __restrict__ Wk, const float* __restrict__ bk,
    const float* __restrict__ Wq, const float* __restrict__ bq,
    const float* __restrict__ Wv, const float* __restrict__ bv,
    const float* __restrict__ Wo,
    _Float16* __restrict__ Qb, _Float16* __restrict__ Kb, _Float16* __restrict__ Vt,
    _Float16* __restrict__ Wof16, float* __restrict__ out)
{
    const int b  = blockIdx.x >> 7;          // 128 blocks per batch
    const int n0 = (blockIdx.x & 127) << 5;  // n-tile of 32
    const int t    = threadIdx.x;
    const int lane = t & 63;
    const int wave = t >> 6;
    const int l15  = lane & 15;
    const int quad = lane >> 4;

    // distributed Wo convert: blocks 0..255 each convert one Wo row
    if (blockIdx.x < 256 && t < 8) {
        float4 wv = ((const float4*)(Wo + blockIdx.x * E_))[t];
        f16x4 tp = {(_Float16)wv.x, (_Float16)wv.y, (_Float16)wv.z, (_Float16)wv.w};
        *(f16x4*)&Wof16[blockIdx.x * E_ + t * 4] = tp;
    }
    if (blockIdx.x == 0 && t == 0)
        out[(size_t)2 * B_ * C_ * N_] = 0.5f;   // gamma (non-learned)

    __shared__ _Float16 xT[32][264];   // x tile transposed [n_local][c], XSWZ'd
    __shared__ _Float16 Wl[32][264];   // current matrix's weights [e][c], XSWZ'd
    __shared__ _Float16 vT[32][44];    // V transpose staging [e][n_local]

    // stage x tile (32 n x 256 c): 8 f16x4-converted float4 loads per thread
    for (int i4 = t; i4 < (32 * 256) / 4; i4 += 256) {
        int j4 = (i4 & 7) * 4;
        int c  = i4 >> 3;
        float4 xv = *(const float4*)(x + (size_t)(b * C_ + c) * N_ + n0 + j4);
        xT[j4 + 0][XSWZ(j4 + 0, c)] = (_Float16)xv.x;
        xT[j4 + 1][XSWZ(j4 + 1, c)] = (_Float16)xv.y;
        xT[j4 + 2][XSWZ(j4 + 2, c)] = (_Float16)xv.z;
        xT[j4 + 3][XSWZ(j4 + 3, c)] = (_Float16)xv.w;
    }

    const float* Ws[3] = {Wk, Wq, Wv};
    const float* bs[3] = {bk, bq, bv};

    const int rowg = wave >> 1;            // n half (0/1)
    const int et   = wave & 1;             // e half (0/1)
    const int row  = rowg * 16 + l15;
    f16x8 Bf[8];

    for (int m = 0; m < 3; ++m) {
        for (int i4 = t; i4 < (E_ * C_) / 4; i4 += 256) {
            float4 wv = ((const float4*)Ws[m])[i4];
            int e = (i4 * 4) >> 8, c = (i4 * 4) & 255;
            f16x4 tp = {(_Float16)wv.x, (_Float16)wv.y, (_Float16)wv.z, (_Float16)wv.w};
            *(f16x4*)&Wl[e][XSWZ(e, c)] = tp;
        }
        __syncthreads();
        if (m == 0) {
            #pragma unroll
            for (int kk = 0; kk < 8; ++kk)
                Bf[kk] = *(const f16x8*)&xT[row][XSWZ(row, kk * 32 + quad * 8)];
        }
        const float sc = (m == 1) ? LOG2E : 1.0f;
        const float* bias = bs[m];
        f32x4 acc = {0.f, 0.f, 0.f, 0.f};
        #pragma unroll
        for (int kk = 0; kk < 8; ++kk) {
            const int e = et * 16 + l15;
            f16x8 Af = *(const f16x8*)&Wl[e][XSWZ(e, kk * 32 + quad * 8)];
            acc = __builtin_amdgcn_mfma_f32_16x16x32_f16(Af, Bf[kk], acc, 0, 0, 0);
        }
        const int n  = n0 + row;
        const int e0 = et * 16 + quad * 4;
        if (m == 2) {
            #pragma unroll
            for (int r = 0; r < 4; ++r)
                vT[e0 + r][row] = (_Float16)(acc[r] + bias[e0 + r]);
        } else {
            f16x4 st;
            #pragma unroll
            for (int r = 0; r < 4; ++r)
                st[r] = (_Float16)((acc[r] + bias[e0 + r]) * sc);
            _Float16* dst = (m == 0) ? Kb : Qb;
            *(f16x4*)&dst[(size_t)(b * N_ + n) * E_ + e0] = st;
        }
        __syncthreads();
    }

    // cooperative V store: exactly one Vt tile (2 KB), 128 threads x f16x8
    if (t < 128) {
        const int e_s = t >> 2;            // 0..31
        const int nb  = t & 3;             // 0..3 (8 n's each)
        f16x8 v = *(const f16x8*)&vT[e_s][nb * 8];
        size_t base = ((size_t)(b * 128 + (n0 >> 5)) * 32 + e_s) * 32 + nb * 8;
        *(f16x8*)&Vt[base] = v;
    }
}

// ---------------------------------------------------------------------------
// Kernel 2 (UNCHANGED from R16-fixed, passing @124.6): flash attention +
// fused output projection, j-tile 32. Kept byte-identical so Δtotal this
// round cleanly attributes to the proj restructure (single-variable A/B).
// ---------------------------------------------------------------------------
__global__ __launch_bounds__(512, 4) void attn_kernel(
    const _Float16* __restrict__ Qb, const _Float16* __restrict__ Kb,
    const _Float16* __restrict__ Vt, const _Float16* __restrict__ Wof16,
    const float* __restrict__ bo, const float* __restrict__ x,
    float* __restrict__ out)
{
    const int wave = threadIdx.x >> 6;     // i-split 0..7 (512 keys each)
    const int lane = threadIdx.x & 63;
    const int l15  = lane & 15, quad = lane >> 4;
    const int jg   = blockIdx.x;           // 0..511
    const int b    = jg >> 7;
    const int j0   = (jg & 127) << 5;      // j-tile of 32

    __shared__ __align__(16) char big[8][2][2176];        // 34.8 KB
    __shared__ float    mls[8][2][2][16];
    __shared__ _Float16 Om[2][16][40];

    f16x8 Qf[2];
    #pragma unroll
    for (int cc = 0; cc < 2; ++cc)
        Qf[cc] = *(const f16x8*)(Qb + (size_t)(b * N_ + j0 + cc * 16 + l15) * E_ + quad * 8);

    f32x4 O0c[2], O1c[2];
    float mrow[2], lsum[2];
    #pragma unroll
    for (int cc = 0; cc < 2; ++cc) {
        O0c[cc] = (f32x4){0, 0, 0, 0}; O1c[cc] = (f32x4){0, 0, 0, 0};
        mrow[cc] = -1e30f; lsum[cc] = 0.f;
    }

    const _Float16* Kp = Kb + (size_t)b * N_ * E_ + (size_t)(wave << 9) * E_;
    const _Float16* Vp = Vt + ((size_t)(b * 128 + wave * 16) << 10);

    // prologue loads (it = 0)
    f16x8 K0 = *(const f16x8*)(Kp + (size_t)l15 * E_ + quad * 8);
    f16x8 K1 = *(const f16x8*)(Kp + (size_t)(16 + l15) * E_ + quad * 8);
    f16x8 Va = *(const f16x8*)(Vp + l15 * 32 + quad * 8);
    f16x8 Vc = *(const f16x8*)(Vp + (16 + l15) * 32 + quad * 8);

    #pragma unroll 2
    for (int it = 0; it < 16; ++it) {
        const int i0n = (it + 1) << 5;    // affine (no wrap): it=15 over-read
                                          // stays inside the 256MiB ws, unused
        f32x4 S0[2], S1[2];
        f32x4 z = {0, 0, 0, 0};
        __builtin_amdgcn_s_setprio(1);
        #pragma unroll
        for (int cc = 0; cc < 2; ++cc) {
            S0[cc] = __builtin_amdgcn_mfma_f32_16x16x32_f16(K0, Qf[cc], z, 0, 0, 0);
            S1[cc] = __builtin_amdgcn_mfma_f32_16x16x32_f16(K1, Qf[cc], z, 0, 0, 0);
        }
        __builtin_amdgcn_s_setprio(0);
        // prefetch next iteration's K (same SSA names)
        K0 = *(const f16x8*)(Kp + (size_t)(i0n + l15) * E_ + quad * 8);
        K1 = *(const f16x8*)(Kp + (size_t)(i0n + 16 + l15) * E_ + quad * 8);

        // ---- phase A: softmax for both cols, P writes to per-col buffers ----
        #pragma unroll
        for (int cc = 0; cc < 2; ++cc) {
            // per-lane max, max3-shaped; no cross-lane on common path
            float mxa = fmaxf(fmaxf(S0[cc][0], S0[cc][1]), S0[cc][2]);
            float mxb = fmaxf(fmaxf(S0[cc][3], S1[cc][0]), S1[cc][1]);
            float mxc = fmaxf(fmaxf(S1[cc][2], S1[cc][3]), mxa);
            float mxl = fmaxf(mxb, mxc);
            if (__any(mxl > mrow[cc] + 8.f)) {     // trigger: reduce + rescale
                float mx = fmaxf(mxl, __shfl_xor(mxl, 16));
                mx = fmaxf(mx, __shfl_xor(mx, 32));
                float mnew  = fmaxf(mrow[cc], mx);
                float alpha = EXP2(mrow[cc] - mnew);
                mrow[cc] = mnew;
                lsum[cc] *= alpha;
                O0c[cc] *= alpha;
                O1c[cc] *= alpha;
            }
            float m0 = mrow[cc];
            float p00 = EXP2(S0[cc][0] - m0), p01 = EXP2(S0[cc][1] - m0);
            float p02 = EXP2(S0[cc][2] - m0), p03 = EXP2(S0[cc][3] - m0);
            float p10 = EXP2(S1[cc][0] - m0), p11 = EXP2(S1[cc][1] - m0);
            float p12 = EXP2(S1[cc][2] - m0), p13 = EXP2(S1[cc][3] - m0);
            lsum[cc] += ((p00 + p01) + (p02 + p03)) + ((p10 + p11) + (p12 + p13));

            // pack via v_cvt_pkrtz_f16_f32 (1 instr per f32 pair)
            f16x2 a0 = PKRTZ(p00, p01);
            f16x2 a1 = PKRTZ(p02, p03);
            f16x2 a2 = PKRTZ(p10, p11);
            f16x2 a3 = PKRTZ(p12, p13);
            f16x4 w0 = {a0[0], a0[1], a1[0], a1[1]};
            f16x4 w1 = {a2[0], a2[1], a3[0], a3[1]};
            _Float16 (*pb)[40] = (_Float16 (*)[40])(big[wave][cc]);
            *(f16x4*)&pb[l15][quad * 4]      = w0;
            *(f16x4*)&pb[l15][16 + quad * 4] = w1;
        }
        // ---- phase B: P reads + PV MFMAs (read latencies overlap) ----
        f16x8 P0, P1;
        {
            _Float16 (*pb0)[40] = (_Float16 (*)[40])(big[wave][0]);
            _Float16 (*pb1)[40] = (_Float16 (*)[40])(big[wave][1]);
            P0 = *(const f16x8*)&pb0[l15][quad * 8];
            P1 = *(const f16x8*)&pb1[l15][quad * 8];
        }
        __builtin_amdgcn_s_setprio(1);
        O0c[0] = __builtin_amdgcn_mfma_f32_16x16x32_f16(Va, P0, O0c[0], 0, 0, 0);
        O1c[0] = __builtin_amdgcn_mfma_f32_16x16x32_f16(Vc, P0, O1c[0], 0, 0, 0);
        O0c[1] = __builtin_amdgcn_mfma_f32_16x16x32_f16(Va, P1, O0c[1], 0, 0, 0);
        O1c[1] = __builtin_amdgcn_mfma_f32_16x16x32_f16(Vc, P1, O1c[1], 0, 0, 0);
        __builtin_amdgcn_s_setprio(0);
        // prefetch next iteration's V (tiled layout: 1KB contiguous)
        Va = *(const f16x8*)(Vp + (i0n << 5) + l15 * 32 + quad * 8);
        Vc = *(const f16x8*)(Vp + (i0n << 5) + (16 + l15) * 32 + quad * 8);
    }

    // publish per-split (m, l) for both cols
    #pragma unroll
    for (int cc = 0; cc < 2; ++cc) {
        float ls = lsum[cc];
        ls += __shfl_xor(ls, 16);
        ls += __shfl_xor(ls, 32);
        if (quad == 0) { mls[wave][0][cc][l15] = mrow[cc]; mls[wave][1][cc][l15] = ls; }
    }
    __syncthreads();

    // LSE combine + osum write, per col
    #pragma unroll
    for (int cc = 0; cc < 2; ++cc) {
        float M = -1e30f, ms[8], ls[8];
        #pragma unroll
        for (int s = 0; s < 8; ++s) {
            ms[s] = mls[s][0][cc][l15]; ls[s] = mls[s][1][cc][l15];
            M = fmaxf(M, ms[s]);
        }
        float L = 0.f;
        #pragma unroll
        for (int s = 0; s < 8; ++s) L += ls[s] * EXP2(ms[s] - M);
        const float w = EXP2(mrow[cc] - M) / L;
        float (*osum)[34] = (float (*)[34])(big[wave][cc]);
        *(f32x4*)&osum[l15][quad * 4]      = O0c[cc] * w;
        *(f32x4*)&osum[l15][16 + quad * 4] = O1c[cc] * w;
    }
    __syncthreads();

    // cross-split sum -> merged O rows (f16); one thread per (j, e), x2 cols
    {
        const int j = threadIdx.x >> 5;    // 0..15
        const int e = threadIdx.x & 31;    // 0..31
        #pragma unroll
        for (int cc = 0; cc < 2; ++cc) {
            float a = 0.f;
            #pragma unroll
            for (int s = 0; s < 8; ++s)
                a += ((const float (*)[34])(big[s][cc]))[j][e];
            Om[cc][j][e] = (_Float16)a;
        }
    }
    __syncthreads();

    // ---- fused output projection: each wave covers 32 channels x 2 cols ----
    f16x8 Bf2[2];
    #pragma unroll
    for (int cc = 0; cc < 2; ++cc)
        Bf2[cc] = *(const f16x8*)&Om[cc][l15][quad * 8];
    float* out_y = out + (size_t)b * C_ * N_;
    float* out_o = out + (size_t)B_ * C_ * N_ + (size_t)b * C_ * N_;
    const float* xb = x + (size_t)b * C_ * N_;
    #pragma unroll
    for (int ct = 0; ct < 2; ++ct) {
        const int c0 = wave * 32 + ct * 16;
        f16x8 Af = *(const f16x8*)(Wof16 + (size_t)(c0 + l15) * E_ + quad * 8);
        f32x4 acc[2];
        f32x4 z = {0, 0, 0, 0};
        #pragma unroll
        for (int cc = 0; cc < 2; ++cc)
            acc[cc] = __builtin_amdgcn_mfma_f32_16x16x32_f16(Af, Bf2[cc], z, 0, 0, 0);
        #pragma unroll
        for (int r = 0; r < 4; ++r) {
            const int c = c0 + quad * 4 + r;
            #pragma unroll
            for (int cc = 0; cc < 2; ++cc) {
                size_t idx = (size_t)c * N_ + j0 + cc * 16 + l15;
                float ov = acc[cc][r] + bo[c];
                out_o[idx] = ov;
                out_y[idx] = 0.5f * ov + xb[idx];
            }
        }
    }
}

// ---------------------------------------------------------------------------
extern "C" void kernel_launch(void* const* d_in, const int* in_sizes, int n_in,
                              void* d_out, int out_size, void* d_ws, size_t ws_size,
                              hipStream_t stream)
{
    const float* x  = (const float*)d_in[0];
    const float* Wk = (const float*)d_in[1];
    const float* bk = (const float*)d_in[2];
    const float* Wq = (const float*)d_in[3];
    const float* bq = (const float*)d_in[4];
    const float* Wv = (const float*)d_in[5];
    const float* bv = (const float*)d_in[6];
    const float* Wo = (const float*)d_in[7];
    const float* bo = (const float*)d_in[8];
    float* out = (float*)d_out;

    char* ws = (char*)d_ws;
    _Float16* Qb    = (_Float16*)(ws);                   // 1 MB  [B][N][E]
    _Float16* Kb    = (_Float16*)(ws + (1u << 20));      // 1 MB  [B][N][E]
    _Float16* Vt    = (_Float16*)(ws + (2u << 20));      // 1 MB  [B][N/32][E][32]
    _Float16* Wof16 = (_Float16*)(ws + (3u << 20));      // 16 KB [C][E]

    // 512 proj blocks (n-tile 32, 2 blocks/CU; x read once)
    proj_kernel<<<dim3(512), dim3(256), 0, stream>>>(
        x, Wk, bk, Wq, bq, Wv, bv, Wo, Qb, Kb, Vt, Wof16, out);
    // 512 attn blocks: j-tile 32, 2 blocks/CU (16 waves/CU)
    attn_kernel<<<dim3(B_ * (N_ / 32)), dim3(512), 0, stream>>>(
        Qb, Kb, Vt, Wof16, bo, x, out);
}

// Round 10
// 122.265 us; speedup vs baseline: 1.4058x; 1.0045x over previous
//
#include <hip/hip_runtime.h>

#define B_ 4
#define C_ 256
#define N_ 4096
#define E_ 32

typedef _Float16 f16x8 __attribute__((ext_vector_type(8)));
typedef _Float16 f16x4 __attribute__((ext_vector_type(4)));
typedef _Float16 f16x2 __attribute__((ext_vector_type(2)));
typedef float f32x4 __attribute__((ext_vector_type(4)));

#define LOG2E 1.44269504088896f
#define EXP2(x) __builtin_amdgcn_exp2f(x)
// cvt_pkrtz returns __fp16x2; bit-identical to f16x2 — bit_cast is free
#define PKRTZ(a, b) __builtin_bit_cast(f16x2, __builtin_amdgcn_cvt_pkrtz((a), (b)))

// LDS column swizzle: breaks bank conflicts of row-strided b128 reads while
// keeping 16B alignment (swizzle unit = 8 f16 = 16 B; same on write & read).
#define XSWZ(row, col) ((col) ^ ((((row) >> 2) & 7) << 3))

// ---------------------------------------------------------------------------
// Kernel 1 (UNCHANGED from R17, passing @122.8): 512 blocks x 256 thr,
// n-tile 32, 2 blocks/CU. Frozen this round so Δtotal attributes to attn.
// ---------------------------------------------------------------------------
__global__ __launch_bounds__(256) void proj_kernel(
    const float* __restrict__ x,
    const float* __restrict__ Wk, const float* __restrict__ bk,
    const float* __restrict__ Wq, const float* __restrict__ bq,
    const float* __restrict__ Wv, const float* __restrict__ bv,
    const float* __restrict__ Wo,
    _Float16* __restrict__ Qb, _Float16* __restrict__ Kb, _Float16* __restrict__ Vt,
    _Float16* __restrict__ Wof16, float* __restrict__ out)
{
    const int b  = blockIdx.x >> 7;          // 128 blocks per batch
    const int n0 = (blockIdx.x & 127) << 5;  // n-tile of 32
    const int t    = threadIdx.x;
    const int lane = t & 63;
    const int wave = t >> 6;
    const int l15  = lane & 15;
    const int quad = lane >> 4;

    // distributed Wo convert: blocks 0..255 each convert one Wo row
    if (blockIdx.x < 256 && t < 8) {
        float4 wv = ((const float4*)(Wo + blockIdx.x * E_))[t];
        f16x4 tp = {(_Float16)wv.x, (_Float16)wv.y, (_Float16)wv.z, (_Float16)wv.w};
        *(f16x4*)&Wof16[blockIdx.x * E_ + t * 4] = tp;
    }
    if (blockIdx.x == 0 && t == 0)
        out[(size_t)2 * B_ * C_ * N_] = 0.5f;   // gamma (non-learned)

    __shared__ _Float16 xT[32][264];   // x tile transposed [n_local][c], XSWZ'd
    __shared__ _Float16 Wl[32][264];   // current matrix's weights [e][c], XSWZ'd
    __shared__ _Float16 vT[32][44];    // V transpose staging [e][n_local]

    for (int i4 = t; i4 < (32 * 256) / 4; i4 += 256) {
        int j4 = (i4 & 7) * 4;
        int c  = i4 >> 3;
        float4 xv = *(const float4*)(x + (size_t)(b * C_ + c) * N_ + n0 + j4);
        xT[j4 + 0][XSWZ(j4 + 0, c)] = (_Float16)xv.x;
        xT[j4 + 1][XSWZ(j4 + 1, c)] = (_Float16)xv.y;
        xT[j4 + 2][XSWZ(j4 + 2, c)] = (_Float16)xv.z;
        xT[j4 + 3][XSWZ(j4 + 3, c)] = (_Float16)xv.w;
    }

    const float* Ws[3] = {Wk, Wq, Wv};
    const float* bs[3] = {bk, bq, bv};

    const int rowg = wave >> 1;            // n half (0/1)
    const int et   = wave & 1;             // e half (0/1)
    const int row  = rowg * 16 + l15;
    f16x8 Bf[8];

    for (int m = 0; m < 3; ++m) {
        for (int i4 = t; i4 < (E_ * C_) / 4; i4 += 256) {
            float4 wv = ((const float4*)Ws[m])[i4];
            int e = (i4 * 4) >> 8, c = (i4 * 4) & 255;
            f16x4 tp = {(_Float16)wv.x, (_Float16)wv.y, (_Float16)wv.z, (_Float16)wv.w};
            *(f16x4*)&Wl[e][XSWZ(e, c)] = tp;
        }
        __syncthreads();
        if (m == 0) {
            #pragma unroll
            for (int kk = 0; kk < 8; ++kk)
                Bf[kk] = *(const f16x8*)&xT[row][XSWZ(row, kk * 32 + quad * 8)];
        }
        const float sc = (m == 1) ? LOG2E : 1.0f;
        const float* bias = bs[m];
        f32x4 acc = {0.f, 0.f, 0.f, 0.f};
        #pragma unroll
        for (int kk = 0; kk < 8; ++kk) {
            const int e = et * 16 + l15;
            f16x8 Af = *(const f16x8*)&Wl[e][XSWZ(e, kk * 32 + quad * 8)];
            acc = __builtin_amdgcn_mfma_f32_16x16x32_f16(Af, Bf[kk], acc, 0, 0, 0);
        }
        const int n  = n0 + row;
        const int e0 = et * 16 + quad * 4;
        if (m == 2) {
            #pragma unroll
            for (int r = 0; r < 4; ++r)
                vT[e0 + r][row] = (_Float16)(acc[r] + bias[e0 + r]);
        } else {
            f16x4 st;
            #pragma unroll
            for (int r = 0; r < 4; ++r)
                st[r] = (_Float16)((acc[r] + bias[e0 + r]) * sc);
            _Float16* dst = (m == 0) ? Kb : Qb;
            *(f16x4*)&dst[(size_t)(b * N_ + n) * E_ + e0] = st;
        }
        __syncthreads();
    }

    // cooperative V store: exactly one Vt tile (2 KB), 128 threads x f16x8
    if (t < 128) {
        const int e_s = t >> 2;            // 0..31
        const int nb  = t & 3;             // 0..3 (8 n's each)
        f16x8 v = *(const f16x8*)&vT[e_s][nb * 8];
        size_t base = ((size_t)(b * 128 + (n0 >> 5)) * 32 + e_s) * 32 + nb * 8;
        *(f16x8*)&Vt[base] = v;
    }
}

// ---------------------------------------------------------------------------
// Kernel 2 (R18): flash attention + fused output projection, j-tile 32.
// VALU-overhead halving vs R16:
//  - KVBLK 64 (4 K-tiles + 4 V-tiles, 8 iters): loop control, __any
//    triggers, rescale bodies, address updates all halve per key. PV chain
//    depth per key unchanged (R12 lesson).
//  - softmax reference folded into the QK MFMA C-operand: S' = K^T Q - mrow
//    comes out of the MFMA directly -> common path p = exp2(S') with ZERO
//    subtracts and a constant trigger compare (S' > 8). Trigger ratchets
//    mc = max(mx', 0) (reference only moves up -> no alpha>1 blowup);
//    mrow=0 init safe: trigger normalizes or P <= 2^8 (defer bound).
// ---------------------------------------------------------------------------
__global__ __launch_bounds__(512, 4) void attn_kernel(
    const _Float16* __restrict__ Qb, const _Float16* __restrict__ Kb,
    const _Float16* __restrict__ Vt, const _Float16* __restrict__ Wof16,
    const float* __restrict__ bo, const float* __restrict__ x,
    float* __restrict__ out)
{
    const int wave = threadIdx.x >> 6;     // i-split 0..7 (512 keys each)
    const int lane = threadIdx.x & 63;
    const int l15  = lane & 15, quad = lane >> 4;
    const int jg   = blockIdx.x;           // 0..511
    const int b    = jg >> 7;
    const int j0   = (jg & 127) << 5;      // j-tile of 32

    // per-wave, per-col 2304B: loop = P bounce [16][72] f16 (keys 0..63);
    // epilogue = osum [16][34] f32 overlay (barrier-separated).
    __shared__ __align__(16) char big[8][2][2304];        // 36.9 KB
    __shared__ float    mls[8][2][2][16];
    __shared__ _Float16 Om[2][16][40];

    f16x8 Qf[2];
    #pragma unroll
    for (int cc = 0; cc < 2; ++cc)
        Qf[cc] = *(const f16x8*)(Qb + (size_t)(b * N_ + j0 + cc * 16 + l15) * E_ + quad * 8);

    f32x4 O0c[2], O1c[2];
    float mneg[2], lsum[2];                // mneg = -mrow (seed value)
    #pragma unroll
    for (int cc = 0; cc < 2; ++cc) {
        O0c[cc] = (f32x4){0, 0, 0, 0}; O1c[cc] = (f32x4){0, 0, 0, 0};
        mneg[cc] = 0.f; lsum[cc] = 0.f;
    }

    const _Float16* Kp = Kb + (size_t)b * N_ * E_ + (size_t)(wave << 9) * E_;
    const _Float16* Vp = Vt + ((size_t)(b * 128 + wave * 16) << 10);

    // prologue loads (keys 0..63 of this wave's range)
    f16x8 K0 = *(const f16x8*)(Kp + (size_t)(l15) * E_ + quad * 8);
    f16x8 K1 = *(const f16x8*)(Kp + (size_t)(16 + l15) * E_ + quad * 8);
    f16x8 K2 = *(const f16x8*)(Kp + (size_t)(32 + l15) * E_ + quad * 8);
    f16x8 K3 = *(const f16x8*)(Kp + (size_t)(48 + l15) * E_ + quad * 8);
    f16x8 Va0 = *(const f16x8*)(Vp + l15 * 32 + quad * 8);
    f16x8 Vc0 = *(const f16x8*)(Vp + (16 + l15) * 32 + quad * 8);
    f16x8 Va1 = *(const f16x8*)(Vp + 1024 + l15 * 32 + quad * 8);
    f16x8 Vc1 = *(const f16x8*)(Vp + 1024 + (16 + l15) * 32 + quad * 8);

    for (int it = 0; it < 8; ++it) {
        const int i0n = (it + 1) << 6;     // affine; last-iter over-read lands
                                           // in allocated ws (harmless)
        f32x4 S[2][4];
        {
            f32x4 c0 = {mneg[0], mneg[0], mneg[0], mneg[0]};
            f32x4 c1 = {mneg[1], mneg[1], mneg[1], mneg[1]};
            __builtin_amdgcn_s_setprio(1);
            S[0][0] = __builtin_amdgcn_mfma_f32_16x16x32_f16(K0, Qf[0], c0, 0, 0, 0);
            S[0][1] = __builtin_amdgcn_mfma_f32_16x16x32_f16(K1, Qf[0], c0, 0, 0, 0);
            S[0][2] = __builtin_amdgcn_mfma_f32_16x16x32_f16(K2, Qf[0], c0, 0, 0, 0);
            S[0][3] = __builtin_amdgcn_mfma_f32_16x16x32_f16(K3, Qf[0], c0, 0, 0, 0);
            S[1][0] = __builtin_amdgcn_mfma_f32_16x16x32_f16(K0, Qf[1], c1, 0, 0, 0);
            S[1][1] = __builtin_amdgcn_mfma_f32_16x16x32_f16(K1, Qf[1], c1, 0, 0, 0);
            S[1][2] = __builtin_amdgcn_mfma_f32_16x16x32_f16(K2, Qf[1], c1, 0, 0, 0);
            S[1][3] = __builtin_amdgcn_mfma_f32_16x16x32_f16(K3, Qf[1], c1, 0, 0, 0);
            __builtin_amdgcn_s_setprio(0);
        }
        // prefetch next iteration's K (same SSA names)
        K0 = *(const f16x8*)(Kp + (size_t)(i0n + l15) * E_ + quad * 8);
        K1 = *(const f16x8*)(Kp + (size_t)(i0n + 16 + l15) * E_ + quad * 8);
        K2 = *(const f16x8*)(Kp + (size_t)(i0n + 32 + l15) * E_ + quad * 8);
        K3 = *(const f16x8*)(Kp + (size_t)(i0n + 48 + l15) * E_ + quad * 8);

        // ---- phase A: softmax both cols (S' is already S - mrow) ----
        #pragma unroll
        for (int cc = 0; cc < 2; ++cc) {
            // max over 16 in-lane scores (max3-shaped)
            float t0 = fmaxf(fmaxf(S[cc][0][0], S[cc][0][1]), S[cc][0][2]);
            float t1 = fmaxf(fmaxf(S[cc][0][3], S[cc][1][0]), S[cc][1][1]);
            float t2 = fmaxf(fmaxf(S[cc][1][2], S[cc][1][3]), S[cc][2][0]);
            float t3 = fmaxf(fmaxf(S[cc][2][1], S[cc][2][2]), S[cc][2][3]);
            float t4 = fmaxf(fmaxf(S[cc][3][0], S[cc][3][1]), S[cc][3][2]);
            float mxl = fmaxf(fmaxf(fmaxf(t0, t1), t2),
                              fmaxf(fmaxf(t3, t4), S[cc][3][3]));
            if (__any(mxl > 8.f)) {        // trigger: reduce, ratchet, rescale
                float mx = fmaxf(mxl, __shfl_xor(mxl, 16));
                mx = fmaxf(mx, __shfl_xor(mx, 32));
                float mc = fmaxf(mx, 0.f); // reference only moves up
                float alpha = EXP2(-mc);
                mneg[cc] -= mc;
                lsum[cc] *= alpha;
                O0c[cc] *= alpha;
                O1c[cc] *= alpha;
                #pragma unroll
                for (int kt = 0; kt < 4; ++kt)
                    #pragma unroll
                    for (int r = 0; r < 4; ++r)
                        S[cc][kt][r] -= mc;   // rare path only
            }
            float p0  = EXP2(S[cc][0][0]), p1  = EXP2(S[cc][0][1]);
            float p2  = EXP2(S[cc][0][2]), p3  = EXP2(S[cc][0][3]);
            float p4  = EXP2(S[cc][1][0]), p5  = EXP2(S[cc][1][1]);
            float p6  = EXP2(S[cc][1][2]), p7  = EXP2(S[cc][1][3]);
            float p8  = EXP2(S[cc][2][0]), p9  = EXP2(S[cc][2][1]);
            float p10 = EXP2(S[cc][2][2]), p11 = EXP2(S[cc][2][3]);
            float p12 = EXP2(S[cc][3][0]), p13 = EXP2(S[cc][3][1]);
            float p14 = EXP2(S[cc][3][2]), p15 = EXP2(S[cc][3][3]);
            lsum[cc] += (((p0 + p1) + (p2 + p3)) + ((p4 + p5) + (p6 + p7)))
                      + (((p8 + p9) + (p10 + p11)) + ((p12 + p13) + (p14 + p15)));

            f16x2 a0 = PKRTZ(p0,  p1),  a1 = PKRTZ(p2,  p3);
            f16x2 a2 = PKRTZ(p4,  p5),  a3 = PKRTZ(p6,  p7);
            f16x2 a4 = PKRTZ(p8,  p9),  a5 = PKRTZ(p10, p11);
            f16x2 a6 = PKRTZ(p12, p13), a7 = PKRTZ(p14, p15);
            f16x4 wA0 = {a0[0], a0[1], a1[0], a1[1]};   // tile 0 (keys 4q+r)
            f16x4 wA1 = {a2[0], a2[1], a3[0], a3[1]};   // tile 1
            f16x4 wB0 = {a4[0], a4[1], a5[0], a5[1]};   // tile 2
            f16x4 wB1 = {a6[0], a6[1], a7[0], a7[1]};   // tile 3
            _Float16 (*pb)[72] = (_Float16 (*)[72])(big[wave][cc]);
            *(f16x4*)&pb[l15][quad * 4]      = wA0;
            *(f16x4*)&pb[l15][16 + quad * 4] = wA1;
            *(f16x4*)&pb[l15][32 + quad * 4] = wB0;
            *(f16x4*)&pb[l15][48 + quad * 4] = wB1;
        }
        // ---- phase B: P reads + PV MFMAs ----
        f16x8 PA0, PB0, PA1, PB1;
        {
            _Float16 (*pb0)[72] = (_Float16 (*)[72])(big[wave][0]);
            _Float16 (*pb1)[72] = (_Float16 (*)[72])(big[wave][1]);
            PA0 = *(const f16x8*)&pb0[l15][quad * 8];
            PB0 = *(const f16x8*)&pb0[l15][32 + quad * 8];
            PA1 = *(const f16x8*)&pb1[l15][quad * 8];
            PB1 = *(const f16x8*)&pb1[l15][32 + quad * 8];
        }
        __builtin_amdgcn_s_setprio(1);
        O0c[0] = __builtin_amdgcn_mfma_f32_16x16x32_f16(Va0, PA0, O0c[0], 0, 0, 0);
        O1c[0] = __builtin_amdgcn_mfma_f32_16x16x32_f16(Vc0, PA0, O1c[0], 0, 0, 0);
        O0c[1] = __builtin_amdgcn_mfma_f32_16x16x32_f16(Va0, PA1, O0c[1], 0, 0, 0);
        O1c[1] = __builtin_amdgcn_mfma_f32_16x16x32_f16(Vc0, PA1, O1c[1], 0, 0, 0);
        O0c[0] = __builtin_amdgcn_mfma_f32_16x16x32_f16(Va1, PB0, O0c[0], 0, 0, 0);
        O1c[0] = __builtin_amdgcn_mfma_f32_16x16x32_f16(Vc1, PB0, O1c[0], 0, 0, 0);
        O0c[1] = __builtin_amdgcn_mfma_f32_16x16x32_f16(Va1, PB1, O0c[1], 0, 0, 0);
        O1c[1] = __builtin_amdgcn_mfma_f32_16x16x32_f16(Vc1, PB1, O1c[1], 0, 0, 0);
        __builtin_amdgcn_s_setprio(0);
        // prefetch next iteration's V (tiled layout: two 2KB tiles)
        Va0 = *(const f16x8*)(Vp + (i0n << 5) + l15 * 32 + quad * 8);
        Vc0 = *(const f16x8*)(Vp + (i0n << 5) + (16 + l15) * 32 + quad * 8);
        Va1 = *(const f16x8*)(Vp + (i0n << 5) + 1024 + l15 * 32 + quad * 8);
        Vc1 = *(const f16x8*)(Vp + (i0n << 5) + 1024 + (16 + l15) * 32 + quad * 8);
    }

    // publish per-split (m, l) for both cols (mrow = -mneg)
    #pragma unroll
    for (int cc = 0; cc < 2; ++cc) {
        float ls = lsum[cc];
        ls += __shfl_xor(ls, 16);
        ls += __shfl_xor(ls, 32);
        if (quad == 0) { mls[wave][0][cc][l15] = -mneg[cc]; mls[wave][1][cc][l15] = ls; }
    }
    __syncthreads();

    // LSE combine + osum write, per col
    #pragma unroll
    for (int cc = 0; cc < 2; ++cc) {
        float M = -1e30f, ms[8], ls[8];
        #pragma unroll
        for (int s = 0; s < 8; ++s) {
            ms[s] = mls[s][0][cc][l15]; ls[s] = mls[s][1][cc][l15];
            M = fmaxf(M, ms[s]);
        }
        float L = 0.f;
        #pragma unroll
        for (int s = 0; s < 8; ++s) L += ls[s] * EXP2(ms[s] - M);
        const float w = EXP2(-mneg[cc] - M) / L;
        float (*osum)[34] = (float (*)[34])(big[wave][cc]);
        *(f32x4*)&osum[l15][quad * 4]      = O0c[cc] * w;
        *(f32x4*)&osum[l15][16 + quad * 4] = O1c[cc] * w;
    }
    __syncthreads();

    // cross-split sum -> merged O rows (f16); one thread per (j, e), x2 cols
    {
        const int j = threadIdx.x >> 5;    // 0..15
        const int e = threadIdx.x & 31;    // 0..31
        #pragma unroll
        for (int cc = 0; cc < 2; ++cc) {
            float a = 0.f;
            #pragma unroll
            for (int s = 0; s < 8; ++s)
                a += ((const float (*)[34])(big[s][cc]))[j][e];
            Om[cc][j][e] = (_Float16)a;
        }
    }
    __syncthreads();

    // ---- fused output projection: each wave covers 32 channels x 2 cols ----
    f16x8 Bf2[2];
    #pragma unroll
    for (int cc = 0; cc < 2; ++cc)
        Bf2[cc] = *(const f16x8*)&Om[cc][l15][quad * 8];
    float* out_y = out + (size_t)b * C_ * N_;
    float* out_o = out + (size_t)B_ * C_ * N_ + (size_t)b * C_ * N_;
    const float* xb = x + (size_t)b * C_ * N_;
    #pragma unroll
    for (int ct = 0; ct < 2; ++ct) {
        const int c0 = wave * 32 + ct * 16;
        f16x8 Af = *(const f16x8*)(Wof16 + (size_t)(c0 + l15) * E_ + quad * 8);
        f32x4 acc[2];
        f32x4 z = {0, 0, 0, 0};
        #pragma unroll
        for (int cc = 0; cc < 2; ++cc)
            acc[cc] = __builtin_amdgcn_mfma_f32_16x16x32_f16(Af, Bf2[cc], z, 0, 0, 0);
        #pragma unroll
        for (int r = 0; r < 4; ++r) {
            const int c = c0 + quad * 4 + r;
            #pragma unroll
            for (int cc = 0; cc < 2; ++cc) {
                size_t idx = (size_t)c * N_ + j0 + cc * 16 + l15;
                float ov = acc[cc][r] + bo[c];
                out_o[idx] = ov;
                out_y[idx] = 0.5f * ov + xb[idx];
            }
        }
    }
}

// ---------------------------------------------------------------------------
extern "C" void kernel_launch(void* const* d_in, const int* in_sizes, int n_in,
                              void* d_out, int out_size, void* d_ws, size_t ws_size,
                              hipStream_t stream)
{
    const float* x  = (const float*)d_in[0];
    const float* Wk = (const float*)d_in[1];
    const float* bk = (const float*)d_in[2];
    const float* Wq = (const float*)d_in[3];
    const float* bq = (const float*)d_in[4];
    const float* Wv = (const float*)d_in[5];
    const float* bv = (const float*)d_in[6];
    const float* Wo = (const float*)d_in[7];
    const float* bo = (const float*)d_in[8];
    float* out = (float*)d_out;

    char* ws = (char*)d_ws;
    _Float16* Qb    = (_Float16*)(ws);                   // 1 MB  [B][N][E]
    _Float16* Kb    = (_Float16*)(ws + (1u << 20));      // 1 MB  [B][N][E]
    _Float16* Vt    = (_Float16*)(ws + (2u << 20));      // 1 MB  [B][N/32][E][32]
    _Float16* Wof16 = (_Float16*)(ws + (3u << 20));      // 16 KB [C][E]

    // 512 proj blocks (n-tile 32, 2 blocks/CU; x read once)
    proj_kernel<<<dim3(512), dim3(256), 0, stream>>>(
        x, Wk, bk, Wq, bq, Wv, bv, Wo, Qb, Kb, Vt, Wof16, out);
    // 512 attn blocks: j-tile 32, KVBLK 64, 2 blocks/CU
    attn_kernel<<<dim3(B_ * (N_ / 32)), dim3(512), 0, stream>>>(
        Qb, Kb, Vt, Wof16, bo, x, out);
}